// Round 1
// baseline (2247.316 us; speedup 1.0000x reference)
//
#include <hip/hip_runtime.h>
#include <math.h>

#define DIMC 128
#define FINC 78
#define REPW 1152   // 9 * 128

// ---------------- utility kernels ----------------

__global__ void k_fill(float* __restrict__ p, float v, int n) {
    int i = blockIdx.x * blockDim.x + threadIdx.x;
    if (i < n) p[i] = v;
}

__global__ void k_deg(const int* __restrict__ dst, float* __restrict__ deg, int E) {
    int e = blockIdx.x * blockDim.x + threadIdx.x;
    if (e < E) atomicAdd(&deg[dst[e]], 1.0f);
}

__global__ void k_rsqrt_inplace(float* __restrict__ p, int n) {
    int i = blockIdx.x * blockDim.x + threadIdx.x;
    if (i < n) p[i] = rsqrtf(p[i]);
}

__global__ void k_wnorm(const int* __restrict__ src, const int* __restrict__ dst,
                        const float* __restrict__ dis, float* __restrict__ wnorm, int E) {
    int e = blockIdx.x * blockDim.x + threadIdx.x;
    if (e < E) wnorm[e] = dis[src[e]] * dis[dst[e]];
}

// start[g] = first index in sorted batch with batch[i] >= g ; start[G] = N
__global__ void k_bounds(const int* __restrict__ batch, int* __restrict__ start, int N, int G) {
    int g = blockIdx.x * blockDim.x + threadIdx.x;
    if (g <= G) {
        int lo = 0, hi = N;
        while (lo < hi) { int mid = (lo + hi) >> 1; if (batch[mid] < g) lo = mid + 1; else hi = mid; }
        start[g] = lo;
    }
}

// ---------------- GEMM: C[N x 128] = act((A (+A2)) @ W + bias) ----------------
// Block: 256 threads, 128 rows x 128 cols, K chunked by KC (K % KC == 0).
// LDS: W chunk [KC x 128] + transposed A chunk [KC x 136-pad].

template<int K, int KC>
__launch_bounds__(256)
__global__ void k_gemm(const float* __restrict__ A, const float* __restrict__ A2,
                       const float* __restrict__ W, const float* __restrict__ bias,
                       float* __restrict__ C, int N, int doRelu) {
    __shared__ __align__(16) float sW[KC * DIMC];
    __shared__ __align__(16) float sA[KC * 136];
    const int tid  = threadIdx.x;
    const int row0 = blockIdx.x * 128;
    const int ty = tid >> 4, tx = tid & 15;
    const int rb = ty * 8, cb = tx * 8;

    float acc[8][8];
#pragma unroll
    for (int i = 0; i < 8; ++i)
#pragma unroll
        for (int j = 0; j < 8; ++j) acc[i][j] = 0.f;

    for (int k0 = 0; k0 < K; k0 += KC) {
        if (k0) __syncthreads();
        // load W chunk (coalesced)
        for (int i = tid; i < KC * DIMC; i += 256) {
            int kk = i >> 7;
            sW[i] = W[(size_t)(k0 + kk) * DIMC + (i & 127)];
        }
        // load A chunk transposed (coalesced reads; strided LDS writes)
        for (int i = tid; i < 128 * KC; i += 256) {
            int r = i / KC, c = i - r * KC;
            int gr = row0 + r;
            float v = 0.f;
            if (gr < N) {
                v = A[(size_t)gr * K + k0 + c];
                if (A2) v += A2[(size_t)gr * K + k0 + c];
            }
            sA[c * 136 + r] = v;
        }
        __syncthreads();

        for (int k = 0; k < KC; ++k) {
            const float4 a0 = *(const float4*)(sA + k * 136 + rb);
            const float4 a1 = *(const float4*)(sA + k * 136 + rb + 4);
            const float4 w0 = *(const float4*)(sW + k * DIMC + cb);
            const float4 w1 = *(const float4*)(sW + k * DIMC + cb + 4);
            const float a[8] = {a0.x, a0.y, a0.z, a0.w, a1.x, a1.y, a1.z, a1.w};
            const float w[8] = {w0.x, w0.y, w0.z, w0.w, w1.x, w1.y, w1.z, w1.w};
#pragma unroll
            for (int i = 0; i < 8; ++i)
#pragma unroll
                for (int j = 0; j < 8; ++j) acc[i][j] = fmaf(a[i], w[j], acc[i][j]);
        }
    }

#pragma unroll
    for (int i = 0; i < 8; ++i) {
        int gr = row0 + rb + i;
        if (gr < N) {
#pragma unroll
            for (int j = 0; j < 8; ++j) {
                float v = acc[i][j];
                if (bias) v += bias[cb + j];
                if (doRelu) v = fmaxf(v, 0.f);
                C[(size_t)gr * DIMC + cb + j] = v;
            }
        }
    }
}

// ---------------- aggregation kernels ----------------

// out[n][c] = t[n][c] * dis[n]^2   (GCN self-loop term, also initializes out)
__global__ void k_self(const float* __restrict__ t, const float* __restrict__ dis,
                       float* __restrict__ out, int NC) {
    int i = blockIdx.x * blockDim.x + threadIdx.x;
    if (i < NC) {
        int r = i >> 7;
        float d = dis[r];
        out[i] = t[i] * d * d;
    }
}

__global__ void k_edge_gcn(const int* __restrict__ src, const int* __restrict__ dst,
                           const float* __restrict__ wnorm, const float* __restrict__ t,
                           float* __restrict__ out, int E) {
    int i = blockIdx.x * blockDim.x + threadIdx.x;
    if (i < E * DIMC) {
        int e = i >> 7, c = i & 127;
        atomicAdd(&out[(size_t)dst[e] * DIMC + c], t[(size_t)src[e] * DIMC + c] * wnorm[e]);
    }
}

template<int D>
__global__ void k_edge_sum(const int* __restrict__ src, const int* __restrict__ dst,
                           const float* __restrict__ h, float* __restrict__ out, int E) {
    int i = blockIdx.x * blockDim.x + threadIdx.x;
    if (i < E * D) {
        int e = i / D, c = i - e * D;
        atomicAdd(&out[(size_t)dst[e] * D + c], h[(size_t)src[e] * D + c]);
    }
}

__global__ void k_bias_relu(const float* __restrict__ t, const float* __restrict__ b,
                            float* __restrict__ out, int NC) {
    int i = blockIdx.x * blockDim.x + threadIdx.x;
    if (i < NC) out[i] = fmaxf(t[i] + b[i & 127], 0.f);
}

// ---------------- batchnorm ----------------

// sums[0..128) = sum(relu(h)), sums[128..256) = sum(relu(h)^2), per column
__global__ void k_bn_stats(const float* __restrict__ h, float* __restrict__ sums, int N) {
    __shared__ float red[512];
    int tid = threadIdx.x;
    int c = tid & 127, half = tid >> 7;
    float s = 0.f, s2 = 0.f;
    for (int r = blockIdx.x * 2 + half; r < N; r += gridDim.x * 2) {
        float v = fmaxf(h[(size_t)r * DIMC + c], 0.f);
        s += v; s2 = fmaf(v, v, s2);
    }
    red[tid] = s; red[256 + tid] = s2;
    __syncthreads();
    if (tid < 128) {
        atomicAdd(&sums[c],        red[tid] + red[tid + 128]);
        atomicAdd(&sums[DIMC + c], red[256 + tid] + red[256 + tid + 128]);
    }
}

__global__ void k_bn_apply(const float* __restrict__ h, const float* __restrict__ sums,
                           const float* __restrict__ gamma, const float* __restrict__ beta,
                           float* __restrict__ xout, float* __restrict__ mAcc,
                           float* __restrict__ eAcc, int NC, int first, float invN) {
    int i = blockIdx.x * blockDim.x + threadIdx.x;
    if (i < NC) {
        int c = i & 127;
        float mu  = sums[c] * invN;
        float var = sums[DIMC + c] * invN - mu * mu;
        float inv = rsqrtf(var + 1e-5f);
        float v = fmaxf(h[i], 0.f);
        float o = (v - mu) * inv * gamma[c] + beta[c];
        xout[i] = o;
        if (first) { mAcc[i] = o; eAcc[i] = o; }
        else       { mAcc[i] *= o; eAcc[i] += o; }
    }
}

// ---------------- segment max (batch sorted -> contiguous ranges) ----------------

__global__ void k_segmax1(const float* __restrict__ X, const int* __restrict__ start,
                          float* __restrict__ out, int group) {
    int g = blockIdx.x, c = threadIdx.x;
    int s = start[g], e = start[g + 1];
    float m = -INFINITY;
    for (int n = s; n < e; ++n) m = fmaxf(m, X[(size_t)n * DIMC + c]);
    out[(size_t)g * REPW + group * DIMC + c] = m;
}

__global__ void k_segmax_me(const float* __restrict__ M, const float* __restrict__ Es,
                            const int* __restrict__ start, float* __restrict__ out) {
    int g = blockIdx.x, c = threadIdx.x;
    int s = start[g], e = start[g + 1];
    float mm = -INFINITY, me = -INFINITY;
    for (int n = s; n < e; ++n) {
        mm = fmaxf(mm, M[(size_t)n * DIMC + c]);
        me = fmaxf(me, Es[(size_t)n * DIMC + c]);
    }
    size_t o = (size_t)g * REPW + c;
    out[o + 3 * DIMC] = mm;
    out[o + 4 * DIMC] = me;
}

__global__ void k_segmax_gcn(const float* __restrict__ G1, const float* __restrict__ G2,
                             const int* __restrict__ start, float* __restrict__ out) {
    int g = blockIdx.x, c = threadIdx.x;
    int s = start[g], e = start[g + 1];
    float m1 = -INFINITY, m2 = -INFINITY, ma = -INFINITY, mm = -INFINITY;
    for (int n = s; n < e; ++n) {
        float a = G1[(size_t)n * DIMC + c], b = G2[(size_t)n * DIMC + c];
        m1 = fmaxf(m1, a); m2 = fmaxf(m2, b);
        ma = fmaxf(ma, a + b); mm = fmaxf(mm, a * b);
    }
    size_t o = (size_t)g * REPW + c;
    out[o + 5 * DIMC] = m1;
    out[o + 6 * DIMC] = m2;
    out[o + 7 * DIMC] = ma;
    out[o + 8 * DIMC] = mm;
}

// ---------------- launch ----------------

extern "C" void kernel_launch(void* const* d_in, const int* in_sizes, int n_in,
                              void* d_out, int out_size, void* d_ws, size_t ws_size,
                              hipStream_t stream) {
    const float* x       = (const float*)d_in[0];
    const int*   ei      = (const int*)d_in[1];
    const int*   batch   = (const int*)d_in[2];
    const float* gcn1_W  = (const float*)d_in[4];
    const float* gcn1_b  = (const float*)d_in[5];
    const float* gcn2_W  = (const float*)d_in[6];
    const float* gcn2_b  = (const float*)d_in[7];
    const float* gin0_w1 = (const float*)d_in[8];
    const float* gin0_b1 = (const float*)d_in[9];
    const float* gin0_w2 = (const float*)d_in[10];
    const float* gin0_b2 = (const float*)d_in[11];
    const float* gin_w1  = (const float*)d_in[12];
    const float* gin_b1  = (const float*)d_in[13];
    const float* gin_w2  = (const float*)d_in[14];
    const float* gin_b2  = (const float*)d_in[15];
    const float* bn_g    = (const float*)d_in[16];
    const float* bn_b    = (const float*)d_in[17];
    float* out = (float*)d_out;

    const int N = in_sizes[0] / FINC;   // 100000
    const int E = in_sizes[1] / 2;      // 400000
    const int G = out_size / REPW;      // 2500
    const int* srcv = ei;
    const int* dstv = ei + E;

    float* ws = (float*)d_ws;
    size_t off = 0;
    auto alloc = [&](size_t n) { float* p = ws + off; off += (n + 63) & ~(size_t)63; return p; };
    float* dis   = alloc(N);
    float* wnorm = alloc(E);
    float* bnsum = alloc(256);
    int*   start = (int*)alloc(G + 1);
    float* bufA  = alloc((size_t)N * DIMC);
    float* bufB  = alloc((size_t)N * DIMC);
    float* bufH  = alloc((size_t)N * DIMC);
    float* mAcc  = alloc((size_t)N * DIMC);
    float* eAcc  = alloc((size_t)N * DIMC);
    (void)ws_size; (void)n_in;

    const int T = 256;
    auto cdiv = [](long a, long b) { return (int)((a + b - 1) / b); };
    const int NC = N * DIMC;
    const int gemmGrid = cdiv(N, 128);
    const float invN = 1.0f / (float)N;

    // degree / norm / graph bounds
    k_fill<<<cdiv(N, T), T, 0, stream>>>(dis, 1.0f, N);
    k_deg<<<cdiv(E, T), T, 0, stream>>>(dstv, dis, E);
    k_rsqrt_inplace<<<cdiv(N, T), T, 0, stream>>>(dis, N);
    k_wnorm<<<cdiv(E, T), T, 0, stream>>>(srcv, dstv, dis, wnorm, E);
    k_bounds<<<cdiv(G + 1, T), T, 0, stream>>>(batch, start, N, G);

    // ---- GCN branch ----
    k_gemm<FINC, 39><<<gemmGrid, 256, 0, stream>>>(x, nullptr, gcn1_W, nullptr, bufA, N, 0);
    k_self<<<cdiv(NC, T), T, 0, stream>>>(bufA, dis, bufB, NC);
    k_edge_gcn<<<cdiv((long)E * DIMC, T), T, 0, stream>>>(srcv, dstv, wnorm, bufA, bufB, E);
    k_bias_relu<<<cdiv(NC, T), T, 0, stream>>>(bufB, gcn1_b, bufH, NC);            // g1
    k_gemm<DIMC, 32><<<gemmGrid, 256, 0, stream>>>(bufH, nullptr, gcn2_W, nullptr, bufA, N, 0);
    k_self<<<cdiv(NC, T), T, 0, stream>>>(bufA, dis, bufB, NC);
    k_edge_gcn<<<cdiv((long)E * DIMC, T), T, 0, stream>>>(srcv, dstv, wnorm, bufA, bufB, E);
    k_bias_relu<<<cdiv(NC, T), T, 0, stream>>>(bufB, gcn2_b, bufA, NC);            // g2
    k_segmax_gcn<<<G, DIMC, 0, stream>>>(bufH, bufA, start, out);                  // groups 5..8

    // ---- GIN layer 0 (K = 78) ----
    k_fill<<<cdiv((long)N * FINC, T), T, 0, stream>>>(bufA, 0.f, N * FINC);
    k_edge_sum<FINC><<<cdiv((long)E * FINC, T), T, 0, stream>>>(srcv, dstv, x, bufA, E);
    k_gemm<FINC, 39><<<gemmGrid, 256, 0, stream>>>(x, bufA, gin0_w1, gin0_b1, bufB, N, 1);   // z
    k_gemm<DIMC, 32><<<gemmGrid, 256, 0, stream>>>(bufB, nullptr, gin0_w2, gin0_b2, bufA, N, 0);
    k_fill<<<1, 256, 0, stream>>>(bnsum, 0.f, 256);
    k_bn_stats<<<256, 256, 0, stream>>>(bufA, bnsum, N);
    k_bn_apply<<<cdiv(NC, T), T, 0, stream>>>(bufA, bnsum, bn_g, bn_b, bufH, mAcc, eAcc, NC, 1, invN);
    k_segmax1<<<G, DIMC, 0, stream>>>(bufH, start, out, 0);                        // group 0

    // ---- GIN layers 1, 2 ----
    for (int L = 1; L <= 2; ++L) {
        const float* w1 = gin_w1 + (size_t)(L - 1) * DIMC * DIMC;
        const float* b1 = gin_b1 + (size_t)(L - 1) * DIMC;
        const float* w2 = gin_w2 + (size_t)(L - 1) * DIMC * DIMC;
        const float* b2 = gin_b2 + (size_t)(L - 1) * DIMC;
        k_fill<<<cdiv(NC, T), T, 0, stream>>>(bufA, 0.f, NC);
        k_edge_sum<DIMC><<<cdiv((long)E * DIMC, T), T, 0, stream>>>(srcv, dstv, bufH, bufA, E);
        k_gemm<DIMC, 32><<<gemmGrid, 256, 0, stream>>>(bufH, bufA, w1, b1, bufB, N, 1);      // z
        k_gemm<DIMC, 32><<<gemmGrid, 256, 0, stream>>>(bufB, nullptr, w2, b2, bufA, N, 0);
        k_fill<<<1, 256, 0, stream>>>(bnsum, 0.f, 256);
        k_bn_stats<<<256, 256, 0, stream>>>(bufA, bnsum, N);
        k_bn_apply<<<cdiv(NC, T), T, 0, stream>>>(bufA, bnsum, bn_g + L * DIMC, bn_b + L * DIMC,
                                                  bufH, mAcc, eAcc, NC, 0, invN);
        k_segmax1<<<G, DIMC, 0, stream>>>(bufH, start, out, L);                    // group L
    }

    k_segmax_me<<<G, DIMC, 0, stream>>>(mAcc, eAcc, start, out);                   // groups 3, 4
}

// Round 2
// 1777.656 us; speedup vs baseline: 1.2642x; 1.2642x over previous
//
#include <hip/hip_runtime.h>
#include <math.h>

#define DIMC 128
#define FINC 78
#define REPW 1152   // 9 * 128

// ---------------- setup kernels ----------------

__global__ void k_fill_int(int* __restrict__ p, int v, int n) {
    int i = blockIdx.x * blockDim.x + threadIdx.x;
    if (i < n) p[i] = v;
}

__global__ void k_fill(float* __restrict__ p, float v, int n) {
    int i = blockIdx.x * blockDim.x + threadIdx.x;
    if (i < n) p[i] = v;
}

__global__ void k_count(const int* __restrict__ dst, int* __restrict__ cnt, int E) {
    int e = blockIdx.x * blockDim.x + threadIdx.x;
    if (e < E) atomicAdd(&cnt[dst[e]], 1);
}

// single-block exclusive scan: rowptr, cursor copy, dis = rsqrt(cnt+1)
__launch_bounds__(1024)
__global__ void k_scan(const int* __restrict__ cnt, int* __restrict__ rowptr,
                       int* __restrict__ cursor, float* __restrict__ dis, int N) {
    __shared__ int sums[1024];
    int t = threadIdx.x;
    int chunk = (N + 1023) >> 10;
    int lo = t * chunk, hi = min(N, lo + chunk);
    int s = 0;
    for (int i = lo; i < hi; ++i) s += cnt[i];
    sums[t] = s;
    __syncthreads();
    for (int d = 1; d < 1024; d <<= 1) {
        int v = (t >= d) ? sums[t - d] : 0;
        __syncthreads();
        sums[t] += v;
        __syncthreads();
    }
    int run = (t == 0) ? 0 : sums[t - 1];
    for (int i = lo; i < hi; ++i) {
        rowptr[i] = run;
        cursor[i] = run;
        dis[i] = rsqrtf((float)cnt[i] + 1.0f);
        run += cnt[i];
    }
    if (t == 1023) rowptr[N] = sums[1023];
}

__global__ void k_scatter(const int* __restrict__ src, const int* __restrict__ dst,
                          int* __restrict__ cursor, int* __restrict__ col, int E) {
    int e = blockIdx.x * blockDim.x + threadIdx.x;
    if (e < E) {
        int pos = atomicAdd(&cursor[dst[e]], 1);
        col[pos] = src[e];
    }
}

// start[g] = first index in sorted batch with batch[i] >= g ; start[G] = N
__global__ void k_bounds(const int* __restrict__ batch, int* __restrict__ start, int N, int G) {
    int g = blockIdx.x * blockDim.x + threadIdx.x;
    if (g <= G) {
        int lo = 0, hi = N;
        while (lo < hi) { int mid = (lo + hi) >> 1; if (batch[mid] < g) lo = mid + 1; else hi = mid; }
        start[g] = lo;
    }
}

// ---------------- GEMM: C[N x 128] = epi(A @ W) ----------------
// epi: optional +bias, optional relu, optional *rowScale (applied last-to-first:
//   v = acc; if bias v += b; if relu v = max(v,0); if rowScale v *= s[row])
// For GCN we call with rowScale only (no bias/relu).

template<int K, int KC>
__launch_bounds__(256)
__global__ void k_gemm(const float* __restrict__ A, const float* __restrict__ W,
                       const float* __restrict__ bias, const float* __restrict__ rowScale,
                       float* __restrict__ C, int N, int doRelu) {
    __shared__ __align__(16) float sW[KC * DIMC];
    __shared__ __align__(16) float sA[KC * 136];
    const int tid  = threadIdx.x;
    const int row0 = blockIdx.x * 128;
    const int ty = tid >> 4, tx = tid & 15;
    const int rb = ty * 8, cb = tx * 8;

    float acc[8][8];
#pragma unroll
    for (int i = 0; i < 8; ++i)
#pragma unroll
        for (int j = 0; j < 8; ++j) acc[i][j] = 0.f;

    for (int k0 = 0; k0 < K; k0 += KC) {
        if (k0) __syncthreads();
        for (int i = tid; i < KC * DIMC; i += 256) {
            int kk = i >> 7;
            sW[i] = W[(size_t)(k0 + kk) * DIMC + (i & 127)];
        }
        for (int i = tid; i < 128 * KC; i += 256) {
            int r = i / KC, c = i - r * KC;
            int gr = row0 + r;
            float v = (gr < N) ? A[(size_t)gr * K + k0 + c] : 0.f;
            sA[c * 136 + r] = v;
        }
        __syncthreads();

        for (int k = 0; k < KC; ++k) {
            const float4 a0 = *(const float4*)(sA + k * 136 + rb);
            const float4 a1 = *(const float4*)(sA + k * 136 + rb + 4);
            const float4 w0 = *(const float4*)(sW + k * DIMC + cb);
            const float4 w1 = *(const float4*)(sW + k * DIMC + cb + 4);
            const float a[8] = {a0.x, a0.y, a0.z, a0.w, a1.x, a1.y, a1.z, a1.w};
            const float w[8] = {w0.x, w0.y, w0.z, w0.w, w1.x, w1.y, w1.z, w1.w};
#pragma unroll
            for (int i = 0; i < 8; ++i)
#pragma unroll
                for (int j = 0; j < 8; ++j) acc[i][j] = fmaf(a[i], w[j], acc[i][j]);
        }
    }

#pragma unroll
    for (int i = 0; i < 8; ++i) {
        int gr = row0 + rb + i;
        if (gr < N) {
            float sc = rowScale ? rowScale[gr] : 1.f;
#pragma unroll
            for (int j = 0; j < 8; ++j) {
                float v = acc[i][j];
                if (bias) v += bias[cb + j];
                if (doRelu) v = fmaxf(v, 0.f);
                C[(size_t)gr * DIMC + cb + j] = v * sc;
            }
        }
    }
}

// ---------------- CSR gather aggregation ----------------
// 32 lanes (float4) per node. t rows for GCN are pre-scaled by dis[row].

// GCN: out[n] = relu( (t'[n] + sum_{e} t'[col[e]]) * dis[n] + bias )
__global__ void k_gather_gcn(const float4* __restrict__ t, const int* __restrict__ rowptr,
                             const int* __restrict__ col, const float* __restrict__ dis,
                             const float4* __restrict__ bias, float4* __restrict__ out, int N) {
    int i = blockIdx.x * blockDim.x + threadIdx.x;
    int node = i >> 5, c4 = i & 31;
    if (node >= N) return;
    int s = rowptr[node], e = rowptr[node + 1];
    float4 acc = t[(size_t)node * 32 + c4];
    for (int k = s; k < e; ++k) {
        float4 v = t[(size_t)col[k] * 32 + c4];
        acc.x += v.x; acc.y += v.y; acc.z += v.z; acc.w += v.w;
    }
    float d = dis[node];
    float4 b = bias[c4];
    float4 o;
    o.x = fmaxf(acc.x * d + b.x, 0.f);
    o.y = fmaxf(acc.y * d + b.y, 0.f);
    o.z = fmaxf(acc.z * d + b.z, 0.f);
    o.w = fmaxf(acc.w * d + b.w, 0.f);
    out[(size_t)node * 32 + c4] = o;
}

// GIN: out[n] = relu( t[n] + sum_{e} t[col[e]] + bias )
__global__ void k_gather_gin(const float4* __restrict__ t, const int* __restrict__ rowptr,
                             const int* __restrict__ col, const float4* __restrict__ bias,
                             float4* __restrict__ out, int N) {
    int i = blockIdx.x * blockDim.x + threadIdx.x;
    int node = i >> 5, c4 = i & 31;
    if (node >= N) return;
    int s = rowptr[node], e = rowptr[node + 1];
    float4 acc = t[(size_t)node * 32 + c4];
    for (int k = s; k < e; ++k) {
        float4 v = t[(size_t)col[k] * 32 + c4];
        acc.x += v.x; acc.y += v.y; acc.z += v.z; acc.w += v.w;
    }
    float4 b = bias[c4];
    float4 o;
    o.x = fmaxf(acc.x + b.x, 0.f);
    o.y = fmaxf(acc.y + b.y, 0.f);
    o.z = fmaxf(acc.z + b.z, 0.f);
    o.w = fmaxf(acc.w + b.w, 0.f);
    out[(size_t)node * 32 + c4] = o;
}

// ---------------- batchnorm (input h already relu'd) ----------------

__global__ void k_bn_stats(const float* __restrict__ h, float* __restrict__ sums, int N) {
    __shared__ float red[512];
    int tid = threadIdx.x;
    int c = tid & 127, half = tid >> 7;
    float s = 0.f, s2 = 0.f;
    for (int r = blockIdx.x * 2 + half; r < N; r += gridDim.x * 2) {
        float v = h[(size_t)r * DIMC + c];
        s += v; s2 = fmaf(v, v, s2);
    }
    red[tid] = s; red[256 + tid] = s2;
    __syncthreads();
    if (tid < 128) {
        atomicAdd(&sums[c],        red[tid] + red[tid + 128]);
        atomicAdd(&sums[DIMC + c], red[256 + tid] + red[256 + tid + 128]);
    }
}

__global__ void k_bn_apply(const float* __restrict__ h, const float* __restrict__ sums,
                           const float* __restrict__ gamma, const float* __restrict__ beta,
                           float* __restrict__ xout, float* __restrict__ mAcc,
                           float* __restrict__ eAcc, int NC, int first, float invN) {
    int i = blockIdx.x * blockDim.x + threadIdx.x;
    if (i < NC) {
        int c = i & 127;
        float mu  = sums[c] * invN;
        float var = sums[DIMC + c] * invN - mu * mu;
        float inv = rsqrtf(var + 1e-5f);
        float o = (h[i] - mu) * inv * gamma[c] + beta[c];
        xout[i] = o;
        if (first) { mAcc[i] = o; eAcc[i] = o; }
        else       { mAcc[i] *= o; eAcc[i] += o; }
    }
}

// ---------------- segment max (batch sorted -> contiguous ranges) ----------------

__global__ void k_segmax1(const float* __restrict__ X, const int* __restrict__ start,
                          float* __restrict__ out, int group) {
    int g = blockIdx.x, c = threadIdx.x;
    int s = start[g], e = start[g + 1];
    float m = -INFINITY;
    for (int n = s; n < e; ++n) m = fmaxf(m, X[(size_t)n * DIMC + c]);
    out[(size_t)g * REPW + group * DIMC + c] = m;
}

__global__ void k_segmax_me(const float* __restrict__ M, const float* __restrict__ Es,
                            const int* __restrict__ start, float* __restrict__ out) {
    int g = blockIdx.x, c = threadIdx.x;
    int s = start[g], e = start[g + 1];
    float mm = -INFINITY, me = -INFINITY;
    for (int n = s; n < e; ++n) {
        mm = fmaxf(mm, M[(size_t)n * DIMC + c]);
        me = fmaxf(me, Es[(size_t)n * DIMC + c]);
    }
    size_t o = (size_t)g * REPW + c;
    out[o + 3 * DIMC] = mm;
    out[o + 4 * DIMC] = me;
}

__global__ void k_segmax_gcn(const float* __restrict__ G1, const float* __restrict__ G2,
                             const int* __restrict__ start, float* __restrict__ out) {
    int g = blockIdx.x, c = threadIdx.x;
    int s = start[g], e = start[g + 1];
    float m1 = -INFINITY, m2 = -INFINITY, ma = -INFINITY, mm = -INFINITY;
    for (int n = s; n < e; ++n) {
        float a = G1[(size_t)n * DIMC + c], b = G2[(size_t)n * DIMC + c];
        m1 = fmaxf(m1, a); m2 = fmaxf(m2, b);
        ma = fmaxf(ma, a + b); mm = fmaxf(mm, a * b);
    }
    size_t o = (size_t)g * REPW + c;
    out[o + 5 * DIMC] = m1;
    out[o + 6 * DIMC] = m2;
    out[o + 7 * DIMC] = ma;
    out[o + 8 * DIMC] = mm;
}

// ---------------- launch ----------------

extern "C" void kernel_launch(void* const* d_in, const int* in_sizes, int n_in,
                              void* d_out, int out_size, void* d_ws, size_t ws_size,
                              hipStream_t stream) {
    const float* x       = (const float*)d_in[0];
    const int*   ei      = (const int*)d_in[1];
    const int*   batch   = (const int*)d_in[2];
    const float* gcn1_W  = (const float*)d_in[4];
    const float* gcn1_b  = (const float*)d_in[5];
    const float* gcn2_W  = (const float*)d_in[6];
    const float* gcn2_b  = (const float*)d_in[7];
    const float* gin0_w1 = (const float*)d_in[8];
    const float* gin0_b1 = (const float*)d_in[9];
    const float* gin0_w2 = (const float*)d_in[10];
    const float* gin0_b2 = (const float*)d_in[11];
    const float* gin_w1  = (const float*)d_in[12];
    const float* gin_b1  = (const float*)d_in[13];
    const float* gin_w2  = (const float*)d_in[14];
    const float* gin_b2  = (const float*)d_in[15];
    const float* bn_g    = (const float*)d_in[16];
    const float* bn_b    = (const float*)d_in[17];
    float* out = (float*)d_out;

    const int N = in_sizes[0] / FINC;   // 100000
    const int E = in_sizes[1] / 2;      // 400000
    const int G = out_size / REPW;      // 2500
    const int* srcv = ei;
    const int* dstv = ei + E;

    float* ws = (float*)d_ws;
    size_t off = 0;
    auto alloc = [&](size_t n) { float* p = ws + off; off += (n + 63) & ~(size_t)63; return p; };
    int*   cnt    = (int*)alloc(N);
    int*   rowptr = (int*)alloc(N + 1);
    int*   cursor = (int*)alloc(N);
    int*   col    = (int*)alloc(E);
    float* dis    = alloc(N);
    float* bnsum  = alloc(256);
    int*   start  = (int*)alloc(G + 1);
    float* bufA   = alloc((size_t)N * DIMC);
    float* bufB   = alloc((size_t)N * DIMC);
    float* bufH   = alloc((size_t)N * DIMC);
    float* mAcc   = alloc((size_t)N * DIMC);
    float* eAcc   = alloc((size_t)N * DIMC);
    (void)ws_size; (void)n_in;

    const int T = 256;
    auto cdiv = [](long a, long b) { return (int)((a + b - 1) / b); };
    const int NC = N * DIMC;
    const int gemmGrid = cdiv(N, 128);
    const int gatherGrid = cdiv((long)N * 32, T);
    const float invN = 1.0f / (float)N;

    // ---- CSR build + norms + graph bounds ----
    k_fill_int<<<cdiv(N, T), T, 0, stream>>>(cnt, 0, N);
    k_count<<<cdiv(E, T), T, 0, stream>>>(dstv, cnt, E);
    k_scan<<<1, 1024, 0, stream>>>(cnt, rowptr, cursor, dis, N);
    k_scatter<<<cdiv(E, T), T, 0, stream>>>(srcv, dstv, cursor, col, E);
    k_bounds<<<cdiv(G + 1, T), T, 0, stream>>>(batch, start, N, G);

    // ---- GCN branch ----
    k_gemm<FINC, 39><<<gemmGrid, 256, 0, stream>>>(x, gcn1_W, nullptr, dis, bufA, N, 0);
    k_gather_gcn<<<gatherGrid, T, 0, stream>>>((const float4*)bufA, rowptr, col, dis,
                                               (const float4*)gcn1_b, (float4*)bufH, N);   // g1
    k_gemm<DIMC, 32><<<gemmGrid, 256, 0, stream>>>(bufH, gcn2_W, nullptr, dis, bufA, N, 0);
    k_gather_gcn<<<gatherGrid, T, 0, stream>>>((const float4*)bufA, rowptr, col, dis,
                                               (const float4*)gcn2_b, (float4*)bufB, N);   // g2
    k_segmax_gcn<<<G, DIMC, 0, stream>>>(bufH, bufB, start, out);                          // groups 5..8

    // ---- GIN layers ----
    const float* w1s[3] = {gin0_w1, gin_w1, gin_w1 + (size_t)DIMC * DIMC};
    const float* b1s[3] = {gin0_b1, gin_b1, gin_b1 + DIMC};
    const float* w2s[3] = {gin0_w2, gin_w2, gin_w2 + (size_t)DIMC * DIMC};
    const float* b2s[3] = {gin0_b2, gin_b2, gin_b2 + DIMC};

    for (int L = 0; L < 3; ++L) {
        // t = h @ w1  (no bias; bias folded into gather epilogue)
        if (L == 0)
            k_gemm<FINC, 39><<<gemmGrid, 256, 0, stream>>>(x, w1s[0], nullptr, nullptr, bufA, N, 0);
        else
            k_gemm<DIMC, 32><<<gemmGrid, 256, 0, stream>>>(bufH, w1s[L], nullptr, nullptr, bufA, N, 0);
        // z = relu(t + agg(t) + b1)
        k_gather_gin<<<gatherGrid, T, 0, stream>>>((const float4*)bufA, rowptr, col,
                                                   (const float4*)b1s[L], (float4*)bufB, N);
        // relu(h) = relu(z @ w2 + b2)   (relu fused; BN consumes relu'd h)
        k_gemm<DIMC, 32><<<gemmGrid, 256, 0, stream>>>(bufB, w2s[L], b2s[L], nullptr, bufA, N, 1);
        k_fill<<<1, 256, 0, stream>>>(bnsum, 0.f, 256);
        k_bn_stats<<<256, 256, 0, stream>>>(bufA, bnsum, N);
        k_bn_apply<<<cdiv(NC, T), T, 0, stream>>>(bufA, bnsum, bn_g + L * DIMC, bn_b + L * DIMC,
                                                  bufH, mAcc, eAcc, NC, L == 0, invN);
        k_segmax1<<<G, DIMC, 0, stream>>>(bufH, start, out, L);                            // group L
    }

    k_segmax_me<<<G, DIMC, 0, stream>>>(mAcc, eAcc, start, out);                           // groups 3, 4
}

// Round 3
// 1510.091 us; speedup vs baseline: 1.4882x; 1.1772x over previous
//
#include <hip/hip_runtime.h>
#include <math.h>

#define DIMC 128
#define FINC 78
#define REPW 1152   // 9 * 128
#define SCAN_TILE 1024   // elements per scan tile (256 threads x 4)

// ---------------- setup kernels ----------------

__global__ void k_fill_int(int* __restrict__ p, int v, int n) {
    int i = blockIdx.x * blockDim.x + threadIdx.x;
    if (i < n) p[i] = v;
}

__global__ void k_fill(float* __restrict__ p, float v, int n) {
    int i = blockIdx.x * blockDim.x + threadIdx.x;
    if (i < n) p[i] = v;
}

__global__ void k_count(const int* __restrict__ dst, int* __restrict__ cnt, int E) {
    int e = blockIdx.x * blockDim.x + threadIdx.x;
    if (e < E) atomicAdd(&cnt[dst[e]], 1);
}

// ---- 3-phase parallel exclusive scan of cnt -> rowptr/cursor, plus dis ----

__launch_bounds__(256)
__global__ void k_tilesum(const int* __restrict__ cnt, int* __restrict__ tileSum, int N) {
    __shared__ int red[256];
    int base = blockIdx.x * SCAN_TILE;
    int s = 0;
    for (int i = threadIdx.x; i < SCAN_TILE; i += 256) {
        int idx = base + i;
        if (idx < N) s += cnt[idx];
    }
    red[threadIdx.x] = s;
    __syncthreads();
    for (int d = 128; d > 0; d >>= 1) {
        if (threadIdx.x < d) red[threadIdx.x] += red[threadIdx.x + d];
        __syncthreads();
    }
    if (threadIdx.x == 0) tileSum[blockIdx.x] = red[0];
}

// single block, T <= 256 tiles: tileOff = exclusive scan; rowptr[N] = total
__launch_bounds__(256)
__global__ void k_tilescan(const int* __restrict__ tileSum, int* __restrict__ tileOff,
                           int* __restrict__ rowptr, int T, int N) {
    __shared__ int sh[256];
    int t = threadIdx.x;
    int orig = (t < T) ? tileSum[t] : 0;
    sh[t] = orig;
    __syncthreads();
    for (int d = 1; d < 256; d <<= 1) {
        int v = (t >= d) ? sh[t - d] : 0;
        __syncthreads();
        sh[t] += v;
        __syncthreads();
    }
    if (t < T) tileOff[t] = sh[t] - orig;     // exclusive
    if (t == 255) rowptr[N] = sh[255];        // total
}

__launch_bounds__(256)
__global__ void k_tileemit(const int* __restrict__ cnt, const int* __restrict__ tileOff,
                           int* __restrict__ rowptr, int* __restrict__ cursor,
                           float* __restrict__ dis, int N) {
    __shared__ int sh[256];
    int t = threadIdx.x;
    int base = blockIdx.x * SCAN_TILE;
    int idx0 = base + t * 4;
    int v0 = 0, v1 = 0, v2 = 0, v3 = 0;
    if (idx0 + 3 < N) {
        int4 v = *(const int4*)(cnt + idx0);
        v0 = v.x; v1 = v.y; v2 = v.z; v3 = v.w;
    } else {
        if (idx0 + 0 < N) v0 = cnt[idx0 + 0];
        if (idx0 + 1 < N) v1 = cnt[idx0 + 1];
        if (idx0 + 2 < N) v2 = cnt[idx0 + 2];
        if (idx0 + 3 < N) v3 = cnt[idx0 + 3];
    }
    int s0 = v0, s1 = s0 + v1, s2 = s1 + v2, s3 = s2 + v3;  // inclusive in-thread
    sh[t] = s3;
    __syncthreads();
    for (int d = 1; d < 256; d <<= 1) {
        int v = (t >= d) ? sh[t - d] : 0;
        __syncthreads();
        sh[t] += v;
        __syncthreads();
    }
    int gbase = tileOff[blockIdx.x] + ((t == 0) ? 0 : sh[t - 1]);
    int ex[4] = {0, s0, s1, s2};
    int vv[4] = {v0, v1, v2, v3};
#pragma unroll
    for (int j = 0; j < 4; ++j) {
        int idx = idx0 + j;
        if (idx < N) {
            int r = gbase + ex[j];
            rowptr[idx] = r;
            cursor[idx] = r;
            dis[idx] = rsqrtf((float)vv[j] + 1.0f);
        }
    }
}

__global__ void k_scatter(const int* __restrict__ src, const int* __restrict__ dst,
                          int* __restrict__ cursor, int* __restrict__ col, int E) {
    int e = blockIdx.x * blockDim.x + threadIdx.x;
    if (e < E) {
        int pos = atomicAdd(&cursor[dst[e]], 1);
        col[pos] = src[e];
    }
}

// start[g] = first index in sorted batch with batch[i] >= g ; start[G] = N
__global__ void k_bounds(const int* __restrict__ batch, int* __restrict__ start, int N, int G) {
    int g = blockIdx.x * blockDim.x + threadIdx.x;
    if (g <= G) {
        int lo = 0, hi = N;
        while (lo < hi) { int mid = (lo + hi) >> 1; if (batch[mid] < g) lo = mid + 1; else hi = mid; }
        start[g] = lo;
    }
}

// ---------------- GEMM: C[N x 128] = epi(A @ W) ----------------

template<int K, int KC>
__launch_bounds__(256)
__global__ void k_gemm(const float* __restrict__ A, const float* __restrict__ W,
                       const float* __restrict__ bias, const float* __restrict__ rowScale,
                       float* __restrict__ C, int N, int doRelu) {
    __shared__ __align__(16) float sW[KC * DIMC];
    __shared__ __align__(16) float sA[KC * 136];
    const int tid  = threadIdx.x;
    const int row0 = blockIdx.x * 128;
    const int ty = tid >> 4, tx = tid & 15;
    const int rb = ty * 8, cb = tx * 8;

    float acc[8][8];
#pragma unroll
    for (int i = 0; i < 8; ++i)
#pragma unroll
        for (int j = 0; j < 8; ++j) acc[i][j] = 0.f;

    for (int k0 = 0; k0 < K; k0 += KC) {
        if (k0) __syncthreads();
        for (int i = tid; i < KC * DIMC; i += 256) {
            int kk = i >> 7;
            sW[i] = W[(size_t)(k0 + kk) * DIMC + (i & 127)];
        }
        for (int i = tid; i < 128 * KC; i += 256) {
            int r = i / KC, c = i - r * KC;
            int gr = row0 + r;
            float v = (gr < N) ? A[(size_t)gr * K + k0 + c] : 0.f;
            sA[c * 136 + r] = v;
        }
        __syncthreads();

        for (int k = 0; k < KC; ++k) {
            const float4 a0 = *(const float4*)(sA + k * 136 + rb);
            const float4 a1 = *(const float4*)(sA + k * 136 + rb + 4);
            const float4 w0 = *(const float4*)(sW + k * DIMC + cb);
            const float4 w1 = *(const float4*)(sW + k * DIMC + cb + 4);
            const float a[8] = {a0.x, a0.y, a0.z, a0.w, a1.x, a1.y, a1.z, a1.w};
            const float w[8] = {w0.x, w0.y, w0.z, w0.w, w1.x, w1.y, w1.z, w1.w};
#pragma unroll
            for (int i = 0; i < 8; ++i)
#pragma unroll
                for (int j = 0; j < 8; ++j) acc[i][j] = fmaf(a[i], w[j], acc[i][j]);
        }
    }

#pragma unroll
    for (int i = 0; i < 8; ++i) {
        int gr = row0 + rb + i;
        if (gr < N) {
            float sc = rowScale ? rowScale[gr] : 1.f;
#pragma unroll
            for (int j = 0; j < 8; ++j) {
                float v = acc[i][j];
                if (bias) v += bias[cb + j];
                if (doRelu) v = fmaxf(v, 0.f);
                C[(size_t)gr * DIMC + cb + j] = v * sc;
            }
        }
    }
}

// ---------------- CSR gather aggregation ----------------

__global__ void k_gather_gcn(const float4* __restrict__ t, const int* __restrict__ rowptr,
                             const int* __restrict__ col, const float* __restrict__ dis,
                             const float4* __restrict__ bias, float4* __restrict__ out, int N) {
    int i = blockIdx.x * blockDim.x + threadIdx.x;
    int node = i >> 5, c4 = i & 31;
    if (node >= N) return;
    int s = rowptr[node], e = rowptr[node + 1];
    float4 acc = t[(size_t)node * 32 + c4];
    for (int k = s; k < e; ++k) {
        float4 v = t[(size_t)col[k] * 32 + c4];
        acc.x += v.x; acc.y += v.y; acc.z += v.z; acc.w += v.w;
    }
    float d = dis[node];
    float4 b = bias[c4];
    float4 o;
    o.x = fmaxf(acc.x * d + b.x, 0.f);
    o.y = fmaxf(acc.y * d + b.y, 0.f);
    o.z = fmaxf(acc.z * d + b.z, 0.f);
    o.w = fmaxf(acc.w * d + b.w, 0.f);
    out[(size_t)node * 32 + c4] = o;
}

__global__ void k_gather_gin(const float4* __restrict__ t, const int* __restrict__ rowptr,
                             const int* __restrict__ col, const float4* __restrict__ bias,
                             float4* __restrict__ out, int N) {
    int i = blockIdx.x * blockDim.x + threadIdx.x;
    int node = i >> 5, c4 = i & 31;
    if (node >= N) return;
    int s = rowptr[node], e = rowptr[node + 1];
    float4 acc = t[(size_t)node * 32 + c4];
    for (int k = s; k < e; ++k) {
        float4 v = t[(size_t)col[k] * 32 + c4];
        acc.x += v.x; acc.y += v.y; acc.z += v.z; acc.w += v.w;
    }
    float4 b = bias[c4];
    float4 o;
    o.x = fmaxf(acc.x + b.x, 0.f);
    o.y = fmaxf(acc.y + b.y, 0.f);
    o.z = fmaxf(acc.z + b.z, 0.f);
    o.w = fmaxf(acc.w + b.w, 0.f);
    out[(size_t)node * 32 + c4] = o;
}

// ---------------- batchnorm (input h already relu'd) ----------------

__global__ void k_bn_stats(const float* __restrict__ h, float* __restrict__ sums, int N) {
    __shared__ float red[512];
    int tid = threadIdx.x;
    int c = tid & 127, half = tid >> 7;
    float s = 0.f, s2 = 0.f;
    for (int r = blockIdx.x * 2 + half; r < N; r += gridDim.x * 2) {
        float v = h[(size_t)r * DIMC + c];
        s += v; s2 = fmaf(v, v, s2);
    }
    red[tid] = s; red[256 + tid] = s2;
    __syncthreads();
    if (tid < 128) {
        atomicAdd(&sums[c],        red[tid] + red[tid + 128]);
        atomicAdd(&sums[DIMC + c], red[256 + tid] + red[256 + tid + 128]);
    }
}

__global__ void k_bn_apply(const float* __restrict__ h, const float* __restrict__ sums,
                           const float* __restrict__ gamma, const float* __restrict__ beta,
                           float* __restrict__ xout, float* __restrict__ mAcc,
                           float* __restrict__ eAcc, int NC, int first, float invN) {
    int i = blockIdx.x * blockDim.x + threadIdx.x;
    if (i < NC) {
        int c = i & 127;
        float mu  = sums[c] * invN;
        float var = sums[DIMC + c] * invN - mu * mu;
        float inv = rsqrtf(var + 1e-5f);
        float o = (h[i] - mu) * inv * gamma[c] + beta[c];
        xout[i] = o;
        if (first) { mAcc[i] = o; eAcc[i] = o; }
        else       { mAcc[i] *= o; eAcc[i] += o; }
    }
}

// ---------------- segment max (batch sorted -> contiguous ranges) ----------------

__global__ void k_segmax1(const float* __restrict__ X, const int* __restrict__ start,
                          float* __restrict__ out, int group) {
    int g = blockIdx.x, c = threadIdx.x;
    int s = start[g], e = start[g + 1];
    float m = -INFINITY;
    for (int n = s; n < e; ++n) m = fmaxf(m, X[(size_t)n * DIMC + c]);
    out[(size_t)g * REPW + group * DIMC + c] = m;
}

__global__ void k_segmax_me(const float* __restrict__ M, const float* __restrict__ Es,
                            const int* __restrict__ start, float* __restrict__ out) {
    int g = blockIdx.x, c = threadIdx.x;
    int s = start[g], e = start[g + 1];
    float mm = -INFINITY, me = -INFINITY;
    for (int n = s; n < e; ++n) {
        mm = fmaxf(mm, M[(size_t)n * DIMC + c]);
        me = fmaxf(me, Es[(size_t)n * DIMC + c]);
    }
    size_t o = (size_t)g * REPW + c;
    out[o + 3 * DIMC] = mm;
    out[o + 4 * DIMC] = me;
}

__global__ void k_segmax_gcn(const float* __restrict__ G1, const float* __restrict__ G2,
                             const int* __restrict__ start, float* __restrict__ out) {
    int g = blockIdx.x, c = threadIdx.x;
    int s = start[g], e = start[g + 1];
    float m1 = -INFINITY, m2 = -INFINITY, ma = -INFINITY, mm = -INFINITY;
    for (int n = s; n < e; ++n) {
        float a = G1[(size_t)n * DIMC + c], b = G2[(size_t)n * DIMC + c];
        m1 = fmaxf(m1, a); m2 = fmaxf(m2, b);
        ma = fmaxf(ma, a + b); mm = fmaxf(mm, a * b);
    }
    size_t o = (size_t)g * REPW + c;
    out[o + 5 * DIMC] = m1;
    out[o + 6 * DIMC] = m2;
    out[o + 7 * DIMC] = ma;
    out[o + 8 * DIMC] = mm;
}

// ---------------- launch ----------------

extern "C" void kernel_launch(void* const* d_in, const int* in_sizes, int n_in,
                              void* d_out, int out_size, void* d_ws, size_t ws_size,
                              hipStream_t stream) {
    const float* x       = (const float*)d_in[0];
    const int*   ei      = (const int*)d_in[1];
    const int*   batch   = (const int*)d_in[2];
    const float* gcn1_W  = (const float*)d_in[4];
    const float* gcn1_b  = (const float*)d_in[5];
    const float* gcn2_W  = (const float*)d_in[6];
    const float* gcn2_b  = (const float*)d_in[7];
    const float* gin0_w1 = (const float*)d_in[8];
    const float* gin0_b1 = (const float*)d_in[9];
    const float* gin0_w2 = (const float*)d_in[10];
    const float* gin0_b2 = (const float*)d_in[11];
    const float* gin_w1  = (const float*)d_in[12];
    const float* gin_b1  = (const float*)d_in[13];
    const float* gin_w2  = (const float*)d_in[14];
    const float* gin_b2  = (const float*)d_in[15];
    const float* bn_g    = (const float*)d_in[16];
    const float* bn_b    = (const float*)d_in[17];
    float* out = (float*)d_out;

    const int N = in_sizes[0] / FINC;   // 100000
    const int E = in_sizes[1] / 2;      // 400000
    const int G = out_size / REPW;      // 2500
    const int* srcv = ei;
    const int* dstv = ei + E;

    float* ws = (float*)d_ws;
    size_t off = 0;
    auto alloc = [&](size_t n) { float* p = ws + off; off += (n + 63) & ~(size_t)63; return p; };
    int*   cnt     = (int*)alloc(N);
    int*   rowptr  = (int*)alloc(N + 1);
    int*   cursor  = (int*)alloc(N);
    int*   col     = (int*)alloc(E);
    float* dis     = alloc(N);
    float* bnsum   = alloc(256);
    int*   start   = (int*)alloc(G + 1);
    int*   tileSum = (int*)alloc(256);
    int*   tileOff = (int*)alloc(256);
    float* bufA    = alloc((size_t)N * DIMC);
    float* bufB    = alloc((size_t)N * DIMC);
    float* bufH    = alloc((size_t)N * DIMC);
    float* mAcc    = alloc((size_t)N * DIMC);
    float* eAcc    = alloc((size_t)N * DIMC);
    (void)ws_size; (void)n_in;

    const int T = 256;
    auto cdiv = [](long a, long b) { return (int)((a + b - 1) / b); };
    const int NC = N * DIMC;
    const int gemmGrid = cdiv(N, 128);
    const int gatherGrid = cdiv((long)N * 32, T);
    const int nTiles = cdiv(N, SCAN_TILE);   // 98 for N=100000 (must be <= 256)
    const float invN = 1.0f / (float)N;

    // ---- CSR build + norms + graph bounds ----
    k_fill_int<<<cdiv(N, T), T, 0, stream>>>(cnt, 0, N);
    k_count<<<cdiv(E, T), T, 0, stream>>>(dstv, cnt, E);
    k_tilesum<<<nTiles, T, 0, stream>>>(cnt, tileSum, N);
    k_tilescan<<<1, T, 0, stream>>>(tileSum, tileOff, rowptr, nTiles, N);
    k_tileemit<<<nTiles, T, 0, stream>>>(cnt, tileOff, rowptr, cursor, dis, N);
    k_scatter<<<cdiv(E, T), T, 0, stream>>>(srcv, dstv, cursor, col, E);
    k_bounds<<<cdiv(G + 1, T), T, 0, stream>>>(batch, start, N, G);

    // ---- GCN branch ----
    k_gemm<FINC, 39><<<gemmGrid, 256, 0, stream>>>(x, gcn1_W, nullptr, dis, bufA, N, 0);
    k_gather_gcn<<<gatherGrid, T, 0, stream>>>((const float4*)bufA, rowptr, col, dis,
                                               (const float4*)gcn1_b, (float4*)bufH, N);   // g1
    k_gemm<DIMC, 32><<<gemmGrid, 256, 0, stream>>>(bufH, gcn2_W, nullptr, dis, bufA, N, 0);
    k_gather_gcn<<<gatherGrid, T, 0, stream>>>((const float4*)bufA, rowptr, col, dis,
                                               (const float4*)gcn2_b, (float4*)bufB, N);   // g2
    k_segmax_gcn<<<G, DIMC, 0, stream>>>(bufH, bufB, start, out);                          // groups 5..8

    // ---- GIN layers ----
    const float* w1s[3] = {gin0_w1, gin_w1, gin_w1 + (size_t)DIMC * DIMC};
    const float* b1s[3] = {gin0_b1, gin_b1, gin_b1 + DIMC};
    const float* w2s[3] = {gin0_w2, gin_w2, gin_w2 + (size_t)DIMC * DIMC};
    const float* b2s[3] = {gin0_b2, gin_b2, gin_b2 + DIMC};

    for (int L = 0; L < 3; ++L) {
        if (L == 0)
            k_gemm<FINC, 39><<<gemmGrid, 256, 0, stream>>>(x, w1s[0], nullptr, nullptr, bufA, N, 0);
        else
            k_gemm<DIMC, 32><<<gemmGrid, 256, 0, stream>>>(bufH, w1s[L], nullptr, nullptr, bufA, N, 0);
        k_gather_gin<<<gatherGrid, T, 0, stream>>>((const float4*)bufA, rowptr, col,
                                                   (const float4*)b1s[L], (float4*)bufB, N);
        k_gemm<DIMC, 32><<<gemmGrid, 256, 0, stream>>>(bufB, w2s[L], b2s[L], nullptr, bufA, N, 1);
        k_fill<<<1, 256, 0, stream>>>(bnsum, 0.f, 256);
        k_bn_stats<<<256, 256, 0, stream>>>(bufA, bnsum, N);
        k_bn_apply<<<cdiv(NC, T), T, 0, stream>>>(bufA, bnsum, bn_g + L * DIMC, bn_b + L * DIMC,
                                                  bufH, mAcc, eAcc, NC, L == 0, invN);
        k_segmax1<<<G, DIMC, 0, stream>>>(bufH, start, out, L);                            // group L
    }

    k_segmax_me<<<G, DIMC, 0, stream>>>(mAcc, eAcc, start, out);                           // groups 3, 4
}

// Round 5
// 1054.095 us; speedup vs baseline: 2.1320x; 1.4326x over previous
//
#include <hip/hip_runtime.h>
#include <math.h>

#define DIMC 128
#define FINC 78
#define REPW 1152        // 9 * 128
#define SCAN_TILE 1024   // elements per scan tile (256 threads x 4)

typedef __attribute__((ext_vector_type(8))) short short8x;
typedef __attribute__((ext_vector_type(4))) float f32x4;

__device__ inline float b2f(unsigned short u) {
    union { unsigned int i; float f; } v; v.i = ((unsigned int)u) << 16; return v.f;
}
__device__ inline unsigned short f2b(float f) {
    union { float f; unsigned int i; } v; v.f = f;
    unsigned int r = (v.i + 0x7FFFu + ((v.i >> 16) & 1u)) >> 16;
    return (unsigned short)r;
}

// ---------------- setup kernels ----------------

__global__ void k_fill_int(int* __restrict__ p, int v, int n) {
    int i = blockIdx.x * blockDim.x + threadIdx.x;
    if (i < n) p[i] = v;
}

__global__ void k_fill(float* __restrict__ p, float v, int n) {
    int i = blockIdx.x * blockDim.x + threadIdx.x;
    if (i < n) p[i] = v;
}

__global__ void k_count(const int* __restrict__ dst, int* __restrict__ cnt, int E) {
    int e = blockIdx.x * blockDim.x + threadIdx.x;
    if (e < E) atomicAdd(&cnt[dst[e]], 1);
}

__launch_bounds__(256)
__global__ void k_tilesum(const int* __restrict__ cnt, int* __restrict__ tileSum, int N) {
    __shared__ int red[256];
    int base = blockIdx.x * SCAN_TILE;
    int s = 0;
    for (int i = threadIdx.x; i < SCAN_TILE; i += 256) {
        int idx = base + i;
        if (idx < N) s += cnt[idx];
    }
    red[threadIdx.x] = s;
    __syncthreads();
    for (int d = 128; d > 0; d >>= 1) {
        if (threadIdx.x < d) red[threadIdx.x] += red[threadIdx.x + d];
        __syncthreads();
    }
    if (threadIdx.x == 0) tileSum[blockIdx.x] = red[0];
}

__launch_bounds__(256)
__global__ void k_tilescan(const int* __restrict__ tileSum, int* __restrict__ tileOff,
                           int* __restrict__ rowptr, int T, int N) {
    __shared__ int sh[256];
    int t = threadIdx.x;
    int orig = (t < T) ? tileSum[t] : 0;
    sh[t] = orig;
    __syncthreads();
    for (int d = 1; d < 256; d <<= 1) {
        int v = (t >= d) ? sh[t - d] : 0;
        __syncthreads();
        sh[t] += v;
        __syncthreads();
    }
    if (t < T) tileOff[t] = sh[t] - orig;
    if (t == 255) rowptr[N] = sh[255];
}

__launch_bounds__(256)
__global__ void k_tileemit(const int* __restrict__ cnt, const int* __restrict__ tileOff,
                           int* __restrict__ rowptr, int* __restrict__ cursor,
                           float* __restrict__ dis, int N) {
    __shared__ int sh[256];
    int t = threadIdx.x;
    int base = blockIdx.x * SCAN_TILE;
    int idx0 = base + t * 4;
    int v0 = 0, v1 = 0, v2 = 0, v3 = 0;
    if (idx0 + 3 < N) {
        int4 v = *(const int4*)(cnt + idx0);
        v0 = v.x; v1 = v.y; v2 = v.z; v3 = v.w;
    } else {
        if (idx0 + 0 < N) v0 = cnt[idx0 + 0];
        if (idx0 + 1 < N) v1 = cnt[idx0 + 1];
        if (idx0 + 2 < N) v2 = cnt[idx0 + 2];
        if (idx0 + 3 < N) v3 = cnt[idx0 + 3];
    }
    int s0 = v0, s1 = s0 + v1, s2 = s1 + v2, s3 = s2 + v3;
    sh[t] = s3;
    __syncthreads();
    for (int d = 1; d < 256; d <<= 1) {
        int v = (t >= d) ? sh[t - d] : 0;
        __syncthreads();
        sh[t] += v;
        __syncthreads();
    }
    int gbase = tileOff[blockIdx.x] + ((t == 0) ? 0 : sh[t - 1]);
    int ex[4] = {0, s0, s1, s2};
    int vv[4] = {v0, v1, v2, v3};
#pragma unroll
    for (int j = 0; j < 4; ++j) {
        int idx = idx0 + j;
        if (idx < N) {
            int r = gbase + ex[j];
            rowptr[idx] = r;
            cursor[idx] = r;
            dis[idx] = rsqrtf((float)vv[j] + 1.0f);
        }
    }
}

__global__ void k_scatter(const int* __restrict__ src, const int* __restrict__ dst,
                          int* __restrict__ cursor, int* __restrict__ col, int E) {
    int e = blockIdx.x * blockDim.x + threadIdx.x;
    if (e < E) {
        int pos = atomicAdd(&cursor[dst[e]], 1);
        col[pos] = src[e];
    }
}

__global__ void k_bounds(const int* __restrict__ batch, int* __restrict__ start, int N, int G) {
    int g = blockIdx.x * blockDim.x + threadIdx.x;
    if (g <= G) {
        int lo = 0, hi = N;
        while (lo < hi) { int mid = (lo + hi) >> 1; if (batch[mid] < g) lo = mid + 1; else hi = mid; }
        start[g] = lo;
    }
}

// ---------------- weight split: fp32 W[k][n] -> transposed bf16 hi/lo [n][k] ----------------

__global__ void k_cvt_w(const float* __restrict__ s0, const float* __restrict__ s1,
                        const float* __restrict__ s2, const float* __restrict__ s3,
                        const float* __restrict__ s4, const float* __restrict__ s5,
                        const float* __restrict__ s6, const float* __restrict__ s7,
                        unsigned short* __restrict__ whi, unsigned short* __restrict__ wlo) {
    int my = blockIdx.y;
    const float* src; int Ksrc, KP; size_t dstoff;
    const size_t o96 = (size_t)128 * 96, o128 = (size_t)128 * 128;
    switch (my) {
        case 0: src = s0; Ksrc = 78;  KP = 96;  dstoff = 0; break;
        case 1: src = s1; Ksrc = 78;  KP = 96;  dstoff = o96; break;
        case 2: src = s2; Ksrc = 128; KP = 128; dstoff = 2 * o96; break;
        case 3: src = s3; Ksrc = 128; KP = 128; dstoff = 2 * o96 + o128; break;
        case 4: src = s4; Ksrc = 128; KP = 128; dstoff = 2 * o96 + 2 * o128; break;
        case 5: src = s5; Ksrc = 128; KP = 128; dstoff = 2 * o96 + 3 * o128; break;
        case 6: src = s6; Ksrc = 128; KP = 128; dstoff = 2 * o96 + 4 * o128; break;
        default: src = s7; Ksrc = 128; KP = 128; dstoff = 2 * o96 + 5 * o128; break;
    }
    int i = blockIdx.x * blockDim.x + threadIdx.x;
    if (i < 128 * KP) {
        int n = i / KP, k = i - n * KP;
        float v = (k < Ksrc) ? src[(size_t)k * DIMC + n] : 0.f;
        unsigned short hi = f2b(v);
        unsigned short lo = f2b(v - b2f(hi));
        whi[dstoff + i] = hi;
        wlo[dstoff + i] = lo;
    }
}

// ---------------- MFMA GEMM (bf16x3 split): C[N x 128] fp32 = epi(A @ W) ----------------
// A fp32 [N x KREAL]; Whi/Wlo bf16 transposed [128 x KP]. 128x128 tile, 4 waves
// of 64x64, K chunked by 32. LDS swizzle: k-group g (8 bf16) of row m at
// (g*128 + ((m+g)&127))*8 ushorts.

template<int KREAL, int KP>
__launch_bounds__(256)
__global__ void k_gemm_mfma3(const float* __restrict__ A,
                             const unsigned short* __restrict__ Whi,
                             const unsigned short* __restrict__ Wlo,
                             const float* __restrict__ bias,
                             const float* __restrict__ rowScale,
                             float* __restrict__ C, int N, int doRelu) {
    __shared__ unsigned short sAhi[128 * 32];
    __shared__ unsigned short sAlo[128 * 32];
    __shared__ unsigned short sBhi[128 * 32];
    __shared__ unsigned short sBlo[128 * 32];
    const int tid = threadIdx.x;
    const int row0 = blockIdx.x * 128;

    const int wave = tid >> 6;
    const int lane = tid & 63;
    const int lm = lane & 15, q = lane >> 4;
    const int wr = (wave >> 1) * 64, wc = (wave & 1) * 64;

    f32x4 acc[4][4];
#pragma unroll
    for (int a = 0; a < 4; ++a)
#pragma unroll
        for (int b = 0; b < 4; ++b) acc[a][b] = (f32x4){0.f, 0.f, 0.f, 0.f};

    for (int k0 = 0; k0 < KP; k0 += 32) {
        if (k0) __syncthreads();
        // stage A chunk: 128 rows x 4 groups; thread handles 2 (row, group) slots
        for (int s = tid; s < 512; s += 256) {
            int r = s >> 2, g = s & 3;
            int gr = row0 + r;
            float v[8];
            int kb = k0 + g * 8;
            if (gr < N) {
                if (KREAL % 8 == 0) {
                    float4 u0 = *(const float4*)(A + (size_t)gr * KREAL + kb);
                    float4 u1 = *(const float4*)(A + (size_t)gr * KREAL + kb + 4);
                    v[0] = u0.x; v[1] = u0.y; v[2] = u0.z; v[3] = u0.w;
                    v[4] = u1.x; v[5] = u1.y; v[6] = u1.z; v[7] = u1.w;
                } else {
#pragma unroll
                    for (int j = 0; j < 8; ++j) {
                        int k = kb + j;
                        v[j] = (k < KREAL) ? A[(size_t)gr * KREAL + k] : 0.f;
                    }
                }
            } else {
#pragma unroll
                for (int j = 0; j < 8; ++j) v[j] = 0.f;
            }
            unsigned int hi[4], lo[4];
#pragma unroll
            for (int j = 0; j < 4; ++j) {
                unsigned short h0 = f2b(v[2 * j]), h1 = f2b(v[2 * j + 1]);
                unsigned short l0 = f2b(v[2 * j] - b2f(h0)), l1 = f2b(v[2 * j + 1] - b2f(h1));
                hi[j] = (unsigned int)h0 | ((unsigned int)h1 << 16);
                lo[j] = (unsigned int)l0 | ((unsigned int)l1 << 16);
            }
            size_t addr = ((size_t)g * 128 + ((r + g) & 127)) * 8;
            *(uint4*)(sAhi + addr) = make_uint4(hi[0], hi[1], hi[2], hi[3]);
            *(uint4*)(sAlo + addr) = make_uint4(lo[0], lo[1], lo[2], lo[3]);
        }
        // stage B chunk
        for (int s = tid; s < 512; s += 256) {
            int n = s >> 2, g = s & 3;
            size_t gaddr = (size_t)n * KP + k0 + g * 8;
            size_t addr = ((size_t)g * 128 + ((n + g) & 127)) * 8;
            *(uint4*)(sBhi + addr) = *(const uint4*)(Whi + gaddr);
            *(uint4*)(sBlo + addr) = *(const uint4*)(Wlo + gaddr);
        }
        __syncthreads();

        short8x ah[4], al[4], bh[4], bl[4];
#pragma unroll
        for (int rt = 0; rt < 4; ++rt) {
            int m = wr + rt * 16 + lm;
            size_t addr = ((size_t)q * 128 + ((m + q) & 127)) * 8;
            ah[rt] = *(const short8x*)(sAhi + addr);
            al[rt] = *(const short8x*)(sAlo + addr);
        }
#pragma unroll
        for (int ct = 0; ct < 4; ++ct) {
            int n = wc + ct * 16 + lm;
            size_t addr = ((size_t)q * 128 + ((n + q) & 127)) * 8;
            bh[ct] = *(const short8x*)(sBhi + addr);
            bl[ct] = *(const short8x*)(sBlo + addr);
        }
#pragma unroll
        for (int rt = 0; rt < 4; ++rt)
#pragma unroll
            for (int ct = 0; ct < 4; ++ct) {
                acc[rt][ct] = __builtin_amdgcn_mfma_f32_16x16x32_bf16(ah[rt], bh[ct], acc[rt][ct], 0, 0, 0);
                acc[rt][ct] = __builtin_amdgcn_mfma_f32_16x16x32_bf16(ah[rt], bl[ct], acc[rt][ct], 0, 0, 0);
                acc[rt][ct] = __builtin_amdgcn_mfma_f32_16x16x32_bf16(al[rt], bh[ct], acc[rt][ct], 0, 0, 0);
            }
    }

    // epilogue: direct fp32 stores (16 consecutive floats per 16-lane group)
#pragma unroll
    for (int rt = 0; rt < 4; ++rt) {
#pragma unroll
        for (int i = 0; i < 4; ++i) {
            int row = wr + rt * 16 + q * 4 + i;
            int gr = row0 + row;
            if (gr < N) {
                float sc = rowScale ? rowScale[gr] : 1.f;
#pragma unroll
                for (int ct = 0; ct < 4; ++ct) {
                    int colg = wc + ct * 16 + lm;
                    float v = acc[rt][ct][i];
                    if (bias) v += bias[colg];
                    if (doRelu) v = fmaxf(v, 0.f);
                    C[(size_t)gr * DIMC + colg] = v * sc;
                }
            }
        }
    }
}

// ---------------- CSR gather aggregation (fp32) ----------------

__global__ void k_gather_gcn(const float4* __restrict__ t, const int* __restrict__ rowptr,
                             const int* __restrict__ col, const float* __restrict__ dis,
                             const float4* __restrict__ bias, float4* __restrict__ out, int N) {
    int i = blockIdx.x * blockDim.x + threadIdx.x;
    int node = i >> 5, c4 = i & 31;
    if (node >= N) return;
    int s = rowptr[node], e = rowptr[node + 1];
    float4 acc = t[(size_t)node * 32 + c4];
    for (int k = s; k < e; ++k) {
        float4 v = t[(size_t)col[k] * 32 + c4];
        acc.x += v.x; acc.y += v.y; acc.z += v.z; acc.w += v.w;
    }
    float d = dis[node];
    float4 b = bias[c4];
    float4 o;
    o.x = fmaxf(acc.x * d + b.x, 0.f);
    o.y = fmaxf(acc.y * d + b.y, 0.f);
    o.z = fmaxf(acc.z * d + b.z, 0.f);
    o.w = fmaxf(acc.w * d + b.w, 0.f);
    out[(size_t)node * 32 + c4] = o;
}

__global__ void k_gather_gin(const float4* __restrict__ t, const int* __restrict__ rowptr,
                             const int* __restrict__ col, const float4* __restrict__ bias,
                             float4* __restrict__ out, int N) {
    int i = blockIdx.x * blockDim.x + threadIdx.x;
    int node = i >> 5, c4 = i & 31;
    if (node >= N) return;
    int s = rowptr[node], e = rowptr[node + 1];
    float4 acc = t[(size_t)node * 32 + c4];
    for (int k = s; k < e; ++k) {
        float4 v = t[(size_t)col[k] * 32 + c4];
        acc.x += v.x; acc.y += v.y; acc.z += v.z; acc.w += v.w;
    }
    float4 b = bias[c4];
    float4 o;
    o.x = fmaxf(acc.x + b.x, 0.f);
    o.y = fmaxf(acc.y + b.y, 0.f);
    o.z = fmaxf(acc.z + b.z, 0.f);
    o.w = fmaxf(acc.w + b.w, 0.f);
    out[(size_t)node * 32 + c4] = o;
}

// ---------------- batchnorm (input h already relu'd) ----------------

__global__ void k_bn_stats(const float* __restrict__ h, float* __restrict__ sums, int N) {
    __shared__ float red[512];
    int tid = threadIdx.x;
    int c = tid & 127, half = tid >> 7;
    float s = 0.f, s2 = 0.f;
    for (int r = blockIdx.x * 2 + half; r < N; r += gridDim.x * 2) {
        float v = h[(size_t)r * DIMC + c];
        s += v; s2 = fmaf(v, v, s2);
    }
    red[tid] = s; red[256 + tid] = s2;
    __syncthreads();
    if (tid < 128) {
        atomicAdd(&sums[c],        red[tid] + red[tid + 128]);
        atomicAdd(&sums[DIMC + c], red[256 + tid] + red[256 + tid + 128]);
    }
}

__global__ void k_bn_apply(const float* __restrict__ h, const float* __restrict__ sums,
                           const float* __restrict__ gamma, const float* __restrict__ beta,
                           float* __restrict__ xout, float* __restrict__ mAcc,
                           float* __restrict__ eAcc, int NC, int first, float invN) {
    int i = blockIdx.x * blockDim.x + threadIdx.x;
    if (i < NC) {
        int c = i & 127;
        float mu  = sums[c] * invN;
        float var = sums[DIMC + c] * invN - mu * mu;
        float inv = rsqrtf(var + 1e-5f);
        float o = (h[i] - mu) * inv * gamma[c] + beta[c];
        xout[i] = o;
        if (first) { mAcc[i] = o; eAcc[i] = o; }
        else       { mAcc[i] *= o; eAcc[i] += o; }
    }
}

// ---------------- segment max ----------------

__global__ void k_segmax1(const float* __restrict__ X, const int* __restrict__ start,
                          float* __restrict__ out, int group) {
    int g = blockIdx.x, c = threadIdx.x;
    int s = start[g], e = start[g + 1];
    float m = -INFINITY;
    for (int n = s; n < e; ++n) m = fmaxf(m, X[(size_t)n * DIMC + c]);
    out[(size_t)g * REPW + group * DIMC + c] = m;
}

__global__ void k_segmax_me(const float* __restrict__ M, const float* __restrict__ Es,
                            const int* __restrict__ start, float* __restrict__ out) {
    int g = blockIdx.x, c = threadIdx.x;
    int s = start[g], e = start[g + 1];
    float mm = -INFINITY, me = -INFINITY;
    for (int n = s; n < e; ++n) {
        mm = fmaxf(mm, M[(size_t)n * DIMC + c]);
        me = fmaxf(me, Es[(size_t)n * DIMC + c]);
    }
    size_t o = (size_t)g * REPW + c;
    out[o + 3 * DIMC] = mm;
    out[o + 4 * DIMC] = me;
}

__global__ void k_segmax_gcn(const float* __restrict__ G1, const float* __restrict__ G2,
                             const int* __restrict__ start, float* __restrict__ out) {
    int g = blockIdx.x, c = threadIdx.x;
    int s = start[g], e = start[g + 1];
    float m1 = -INFINITY, m2 = -INFINITY, ma = -INFINITY, mm = -INFINITY;
    for (int n = s; n < e; ++n) {
        float a = G1[(size_t)n * DIMC + c], b = G2[(size_t)n * DIMC + c];
        m1 = fmaxf(m1, a); m2 = fmaxf(m2, b);
        ma = fmaxf(ma, a + b); mm = fmaxf(mm, a * b);
    }
    size_t o = (size_t)g * REPW + c;
    out[o + 5 * DIMC] = m1;
    out[o + 6 * DIMC] = m2;
    out[o + 7 * DIMC] = ma;
    out[o + 8 * DIMC] = mm;
}

// ---------------- launch ----------------

extern "C" void kernel_launch(void* const* d_in, const int* in_sizes, int n_in,
                              void* d_out, int out_size, void* d_ws, size_t ws_size,
                              hipStream_t stream) {
    const float* x       = (const float*)d_in[0];
    const int*   ei      = (const int*)d_in[1];
    const int*   batch   = (const int*)d_in[2];
    const float* gcn1_W  = (const float*)d_in[4];
    const float* gcn1_b  = (const float*)d_in[5];
    const float* gcn2_W  = (const float*)d_in[6];
    const float* gcn2_b  = (const float*)d_in[7];
    const float* gin0_w1 = (const float*)d_in[8];
    const float* gin0_b1 = (const float*)d_in[9];
    const float* gin0_w2 = (const float*)d_in[10];
    const float* gin0_b2 = (const float*)d_in[11];
    const float* gin_w1  = (const float*)d_in[12];
    const float* gin_b1  = (const float*)d_in[13];
    const float* gin_w2  = (const float*)d_in[14];
    const float* gin_b2  = (const float*)d_in[15];
    const float* bn_g    = (const float*)d_in[16];
    const float* bn_b    = (const float*)d_in[17];
    float* out = (float*)d_out;

    const int N = in_sizes[0] / FINC;   // 100000
    const int E = in_sizes[1] / 2;      // 400000
    const int G = out_size / REPW;      // 2500
    const int* srcv = ei;
    const int* dstv = ei + E;

    char* ws = (char*)d_ws;
    size_t off = 0;
    auto alloc = [&](size_t bytes) { char* p = ws + off; off += (bytes + 255) & ~(size_t)255; return p; };
    int*   cnt     = (int*)alloc(N * 4);
    int*   rowptr  = (int*)alloc((N + 1) * 4);
    int*   cursor  = (int*)alloc(N * 4);
    int*   col     = (int*)alloc(E * 4);
    float* dis     = (float*)alloc(N * 4);
    float* bnsum   = (float*)alloc(256 * 4);
    int*   start   = (int*)alloc((G + 1) * 4);
    int*   tileSum = (int*)alloc(256 * 4);
    int*   tileOff = (int*)alloc(256 * 4);
    const size_t wtElems = 2 * (size_t)128 * 96 + 6 * (size_t)128 * 128;
    unsigned short* whi = (unsigned short*)alloc(wtElems * 2);
    unsigned short* wlo = (unsigned short*)alloc(wtElems * 2);
    float* bufA    = (float*)alloc((size_t)N * DIMC * 4);
    float* bufB    = (float*)alloc((size_t)N * DIMC * 4);
    float* bufH    = (float*)alloc((size_t)N * DIMC * 4);
    float* mAcc    = (float*)alloc((size_t)N * DIMC * 4);
    float* eAcc    = (float*)alloc((size_t)N * DIMC * 4);
    (void)ws_size; (void)n_in;

    const size_t o96 = (size_t)128 * 96, o128 = (size_t)128 * 128;
    const size_t woff[8] = {0, o96, 2 * o96, 2 * o96 + o128, 2 * o96 + 2 * o128,
                            2 * o96 + 3 * o128, 2 * o96 + 4 * o128, 2 * o96 + 5 * o128};
    // order: gcn1, gin0_w1, gcn2, gin0_w2, gin_w1[0], gin_w1[1], gin_w2[0], gin_w2[1]

    const int T = 256;
    auto cdiv = [](long a, long b) { return (int)((a + b - 1) / b); };
    const int NC = N * DIMC;
    const int gemmGrid = cdiv(N, 128);
    const int gatherGrid = cdiv((long)N * 32, T);
    const int nTiles = cdiv(N, SCAN_TILE);
    const float invN = 1.0f / (float)N;

    // ---- CSR build + norms + graph bounds + weight split ----
    k_fill_int<<<cdiv(N, T), T, 0, stream>>>(cnt, 0, N);
    k_count<<<cdiv(E, T), T, 0, stream>>>(dstv, cnt, E);
    k_tilesum<<<nTiles, T, 0, stream>>>(cnt, tileSum, N);
    k_tilescan<<<1, T, 0, stream>>>(tileSum, tileOff, rowptr, nTiles, N);
    k_tileemit<<<nTiles, T, 0, stream>>>(cnt, tileOff, rowptr, cursor, dis, N);
    k_scatter<<<cdiv(E, T), T, 0, stream>>>(srcv, dstv, cursor, col, E);
    k_bounds<<<cdiv(G + 1, T), T, 0, stream>>>(batch, start, N, G);
    {
        dim3 g(64, 8);
        k_cvt_w<<<g, T, 0, stream>>>(gcn1_W, gin0_w1, gcn2_W, gin0_w2,
                                     gin_w1, gin_w1 + o128, gin_w2, gin_w2 + o128, whi, wlo);
    }

    // ---- GCN branch ----
    k_gemm_mfma3<FINC, 96><<<gemmGrid, T, 0, stream>>>(x, whi + woff[0], wlo + woff[0],
                                                       nullptr, dis, bufA, N, 0);
    k_gather_gcn<<<gatherGrid, T, 0, stream>>>((const float4*)bufA, rowptr, col, dis,
                                               (const float4*)gcn1_b, (float4*)bufH, N);   // g1
    k_gemm_mfma3<DIMC, 128><<<gemmGrid, T, 0, stream>>>(bufH, whi + woff[2], wlo + woff[2],
                                                        nullptr, dis, bufA, N, 0);
    k_gather_gcn<<<gatherGrid, T, 0, stream>>>((const float4*)bufA, rowptr, col, dis,
                                               (const float4*)gcn2_b, (float4*)bufB, N);   // g2
    k_segmax_gcn<<<G, DIMC, 0, stream>>>(bufH, bufB, start, out);                          // groups 5..8

    // ---- GIN layers ----
    const int w1i[3] = {1, 4, 5};
    const int w2i[3] = {3, 6, 7};
    const float* b1s[3] = {gin0_b1, gin_b1, gin_b1 + DIMC};
    const float* b2s[3] = {gin0_b2, gin_b2, gin_b2 + DIMC};

    for (int L = 0; L < 3; ++L) {
        if (L == 0)
            k_gemm_mfma3<FINC, 96><<<gemmGrid, T, 0, stream>>>(x, whi + woff[1], wlo + woff[1],
                                                               nullptr, nullptr, bufA, N, 0);
        else
            k_gemm_mfma3<DIMC, 128><<<gemmGrid, T, 0, stream>>>(bufH, whi + woff[w1i[L]], wlo + woff[w1i[L]],
                                                                nullptr, nullptr, bufA, N, 0);
        k_gather_gin<<<gatherGrid, T, 0, stream>>>((const float4*)bufA, rowptr, col,
                                                   (const float4*)b1s[L], (float4*)bufB, N);
        k_gemm_mfma3<DIMC, 128><<<gemmGrid, T, 0, stream>>>(bufB, whi + woff[w2i[L]], wlo + woff[w2i[L]],
                                                            b2s[L], nullptr, bufA, N, 1);
        k_fill<<<1, T, 0, stream>>>(bnsum, 0.f, 256);
        k_bn_stats<<<256, T, 0, stream>>>(bufA, bnsum, N);
        k_bn_apply<<<cdiv(NC, T), T, 0, stream>>>(bufA, bnsum, bn_g + L * DIMC, bn_b + L * DIMC,
                                                  bufH, mAcc, eAcc, NC, L == 0, invN);
        k_segmax1<<<G, DIMC, 0, stream>>>(bufH, start, out, L);                            // group L
    }

    k_segmax_me<<<G, DIMC, 0, stream>>>(mAcc, eAcc, start, out);                           // groups 3, 4
}

// Round 6
// 794.118 us; speedup vs baseline: 2.8300x; 1.3274x over previous
//
#include <hip/hip_runtime.h>
#include <math.h>

#define DIMC 128
#define FINC 78
#define REPW 1152        // 9 * 128
#define SCAN_TILE 1024   // elements per scan tile (256 threads x 4)

typedef __attribute__((ext_vector_type(8))) short short8x;
typedef __attribute__((ext_vector_type(4))) float f32x4;

__device__ inline float b2f(unsigned short u) {
    union { unsigned int i; float f; } v; v.i = ((unsigned int)u) << 16; return v.f;
}
__device__ inline unsigned short f2b(float f) {
    union { float f; unsigned int i; } v; v.f = f;
    unsigned int r = (v.i + 0x7FFFu + ((v.i >> 16) & 1u)) >> 16;
    return (unsigned short)r;
}

// ---------------- setup kernels ----------------

__global__ void k_fill_int(int* __restrict__ p, int v, int n) {
    int i = blockIdx.x * blockDim.x + threadIdx.x;
    if (i < n) p[i] = v;
}

__global__ void k_fill(float* __restrict__ p, float v, int n) {
    int i = blockIdx.x * blockDim.x + threadIdx.x;
    if (i < n) p[i] = v;
}

__global__ void k_count(const int* __restrict__ dst, int* __restrict__ cnt, int E) {
    int e = blockIdx.x * blockDim.x + threadIdx.x;
    if (e < E) atomicAdd(&cnt[dst[e]], 1);
}

__launch_bounds__(256)
__global__ void k_tilesum(const int* __restrict__ cnt, int* __restrict__ tileSum, int N) {
    __shared__ int red[256];
    int base = blockIdx.x * SCAN_TILE;
    int s = 0;
    for (int i = threadIdx.x; i < SCAN_TILE; i += 256) {
        int idx = base + i;
        if (idx < N) s += cnt[idx];
    }
    red[threadIdx.x] = s;
    __syncthreads();
    for (int d = 128; d > 0; d >>= 1) {
        if (threadIdx.x < d) red[threadIdx.x] += red[threadIdx.x + d];
        __syncthreads();
    }
    if (threadIdx.x == 0) tileSum[blockIdx.x] = red[0];
}

__launch_bounds__(256)
__global__ void k_tilescan(const int* __restrict__ tileSum, int* __restrict__ tileOff,
                           int* __restrict__ rowptr, int T, int N) {
    __shared__ int sh[256];
    int t = threadIdx.x;
    int orig = (t < T) ? tileSum[t] : 0;
    sh[t] = orig;
    __syncthreads();
    for (int d = 1; d < 256; d <<= 1) {
        int v = (t >= d) ? sh[t - d] : 0;
        __syncthreads();
        sh[t] += v;
        __syncthreads();
    }
    if (t < T) tileOff[t] = sh[t] - orig;
    if (t == 255) rowptr[N] = sh[255];
}

__launch_bounds__(256)
__global__ void k_tileemit(const int* __restrict__ cnt, const int* __restrict__ tileOff,
                           int* __restrict__ rowptr, int* __restrict__ cursor,
                           float* __restrict__ dis, int N) {
    __shared__ int sh[256];
    int t = threadIdx.x;
    int base = blockIdx.x * SCAN_TILE;
    int idx0 = base + t * 4;
    int v0 = 0, v1 = 0, v2 = 0, v3 = 0;
    if (idx0 + 3 < N) {
        int4 v = *(const int4*)(cnt + idx0);
        v0 = v.x; v1 = v.y; v2 = v.z; v3 = v.w;
    } else {
        if (idx0 + 0 < N) v0 = cnt[idx0 + 0];
        if (idx0 + 1 < N) v1 = cnt[idx0 + 1];
        if (idx0 + 2 < N) v2 = cnt[idx0 + 2];
        if (idx0 + 3 < N) v3 = cnt[idx0 + 3];
    }
    int s0 = v0, s1 = s0 + v1, s2 = s1 + v2, s3 = s2 + v3;
    sh[t] = s3;
    __syncthreads();
    for (int d = 1; d < 256; d <<= 1) {
        int v = (t >= d) ? sh[t - d] : 0;
        __syncthreads();
        sh[t] += v;
        __syncthreads();
    }
    int gbase = tileOff[blockIdx.x] + ((t == 0) ? 0 : sh[t - 1]);
    int ex[4] = {0, s0, s1, s2};
    int vv[4] = {v0, v1, v2, v3};
#pragma unroll
    for (int j = 0; j < 4; ++j) {
        int idx = idx0 + j;
        if (idx < N) {
            int r = gbase + ex[j];
            rowptr[idx] = r;
            cursor[idx] = r;
            dis[idx] = rsqrtf((float)vv[j] + 1.0f);
        }
    }
}

__global__ void k_scatter(const int* __restrict__ src, const int* __restrict__ dst,
                          int* __restrict__ cursor, int* __restrict__ col, int E) {
    int e = blockIdx.x * blockDim.x + threadIdx.x;
    if (e < E) {
        int pos = atomicAdd(&cursor[dst[e]], 1);
        col[pos] = src[e];
    }
}

__global__ void k_bounds(const int* __restrict__ batch, int* __restrict__ start, int N, int G) {
    int g = blockIdx.x * blockDim.x + threadIdx.x;
    if (g <= G) {
        int lo = 0, hi = N;
        while (lo < hi) { int mid = (lo + hi) >> 1; if (batch[mid] < g) lo = mid + 1; else hi = mid; }
        start[g] = lo;
    }
}

// ---------------- weight split: fp32 W[k][n] -> transposed bf16 hi/lo [n][k] ----------------

__global__ void k_cvt_w(const float* __restrict__ s0, const float* __restrict__ s1,
                        const float* __restrict__ s2, const float* __restrict__ s3,
                        const float* __restrict__ s4, const float* __restrict__ s5,
                        const float* __restrict__ s6, const float* __restrict__ s7,
                        unsigned short* __restrict__ whi, unsigned short* __restrict__ wlo) {
    int my = blockIdx.y;
    const float* src; int Ksrc, KP; size_t dstoff;
    const size_t o96 = (size_t)128 * 96, o128 = (size_t)128 * 128;
    switch (my) {
        case 0: src = s0; Ksrc = 78;  KP = 96;  dstoff = 0; break;
        case 1: src = s1; Ksrc = 78;  KP = 96;  dstoff = o96; break;
        case 2: src = s2; Ksrc = 128; KP = 128; dstoff = 2 * o96; break;
        case 3: src = s3; Ksrc = 128; KP = 128; dstoff = 2 * o96 + o128; break;
        case 4: src = s4; Ksrc = 128; KP = 128; dstoff = 2 * o96 + 2 * o128; break;
        case 5: src = s5; Ksrc = 128; KP = 128; dstoff = 2 * o96 + 3 * o128; break;
        case 6: src = s6; Ksrc = 128; KP = 128; dstoff = 2 * o96 + 4 * o128; break;
        default: src = s7; Ksrc = 128; KP = 128; dstoff = 2 * o96 + 5 * o128; break;
    }
    int i = blockIdx.x * blockDim.x + threadIdx.x;
    if (i < 128 * KP) {
        int n = i / KP, k = i - n * KP;
        float v = (k < Ksrc) ? src[(size_t)k * DIMC + n] : 0.f;
        unsigned short hi = f2b(v);
        unsigned short lo = f2b(v - b2f(hi));
        whi[dstoff + i] = hi;
        wlo[dstoff + i] = lo;
    }
}

// ---------------- MFMA GEMM (bf16x3 split): C[N x 128] fp32 = epi(A' @ W) ----------------
// A fp32 [N x KREAL]; optional per-column affine on A during staging
// (A' = A*inScale[k]+inShift[k], for deferred batchnorm). Whi/Wlo bf16
// transposed [128 x KP]. Optional fused column stats (sum, sumsq) of the
// epilogue output into statsOut[256] via LDS + global atomics.

template<int KREAL, int KP>
__launch_bounds__(256)
__global__ void k_gemm_mfma3(const float* __restrict__ A,
                             const unsigned short* __restrict__ Whi,
                             const unsigned short* __restrict__ Wlo,
                             const float* __restrict__ bias,
                             const float* __restrict__ rowScale,
                             const float* __restrict__ inScale,
                             const float* __restrict__ inShift,
                             float* __restrict__ statsOut,
                             float* __restrict__ C, int N, int doRelu) {
    __shared__ unsigned short sAhi[128 * 32];
    __shared__ unsigned short sAlo[128 * 32];
    __shared__ unsigned short sBhi[128 * 32];
    __shared__ unsigned short sBlo[128 * 32];
    __shared__ float sStats[256];
    const int tid = threadIdx.x;
    const int row0 = blockIdx.x * 128;

    const int wave = tid >> 6;
    const int lane = tid & 63;
    const int lm = lane & 15, q = lane >> 4;
    const int wr = (wave >> 1) * 64, wc = (wave & 1) * 64;

    f32x4 acc[4][4];
#pragma unroll
    for (int a = 0; a < 4; ++a)
#pragma unroll
        for (int b = 0; b < 4; ++b) acc[a][b] = (f32x4){0.f, 0.f, 0.f, 0.f};

    for (int k0 = 0; k0 < KP; k0 += 32) {
        if (k0) __syncthreads();
        // stage A chunk: 128 rows x 4 groups of 8
        for (int s = tid; s < 512; s += 256) {
            int r = s >> 2, g = s & 3;
            int gr = row0 + r;
            float v[8];
            int kb = k0 + g * 8;
            if (gr < N) {
                if (KREAL % 8 == 0) {
                    float4 u0 = *(const float4*)(A + (size_t)gr * KREAL + kb);
                    float4 u1 = *(const float4*)(A + (size_t)gr * KREAL + kb + 4);
                    v[0] = u0.x; v[1] = u0.y; v[2] = u0.z; v[3] = u0.w;
                    v[4] = u1.x; v[5] = u1.y; v[6] = u1.z; v[7] = u1.w;
                } else {
#pragma unroll
                    for (int j = 0; j < 8; ++j) {
                        int k = kb + j;
                        v[j] = (k < KREAL) ? A[(size_t)gr * KREAL + k] : 0.f;
                    }
                }
                if (inScale) {
#pragma unroll
                    for (int j = 0; j < 8; ++j) {
                        int k = kb + j;
                        v[j] = fmaf(v[j], inScale[k], inShift[k]);
                    }
                }
            } else {
#pragma unroll
                for (int j = 0; j < 8; ++j) v[j] = 0.f;
            }
            unsigned int hi[4], lo[4];
#pragma unroll
            for (int j = 0; j < 4; ++j) {
                unsigned short h0 = f2b(v[2 * j]), h1 = f2b(v[2 * j + 1]);
                unsigned short l0 = f2b(v[2 * j] - b2f(h0)), l1 = f2b(v[2 * j + 1] - b2f(h1));
                hi[j] = (unsigned int)h0 | ((unsigned int)h1 << 16);
                lo[j] = (unsigned int)l0 | ((unsigned int)l1 << 16);
            }
            size_t addr = ((size_t)g * 128 + ((r + g) & 127)) * 8;
            *(uint4*)(sAhi + addr) = make_uint4(hi[0], hi[1], hi[2], hi[3]);
            *(uint4*)(sAlo + addr) = make_uint4(lo[0], lo[1], lo[2], lo[3]);
        }
        // stage B chunk
        for (int s = tid; s < 512; s += 256) {
            int n = s >> 2, g = s & 3;
            size_t gaddr = (size_t)n * KP + k0 + g * 8;
            size_t addr = ((size_t)g * 128 + ((n + g) & 127)) * 8;
            *(uint4*)(sBhi + addr) = *(const uint4*)(Whi + gaddr);
            *(uint4*)(sBlo + addr) = *(const uint4*)(Wlo + gaddr);
        }
        __syncthreads();

        short8x ah[4], al[4], bh[4], bl[4];
#pragma unroll
        for (int rt = 0; rt < 4; ++rt) {
            int m = wr + rt * 16 + lm;
            size_t addr = ((size_t)q * 128 + ((m + q) & 127)) * 8;
            ah[rt] = *(const short8x*)(sAhi + addr);
            al[rt] = *(const short8x*)(sAlo + addr);
        }
#pragma unroll
        for (int ct = 0; ct < 4; ++ct) {
            int n = wc + ct * 16 + lm;
            size_t addr = ((size_t)q * 128 + ((n + q) & 127)) * 8;
            bh[ct] = *(const short8x*)(sBhi + addr);
            bl[ct] = *(const short8x*)(sBlo + addr);
        }
#pragma unroll
        for (int rt = 0; rt < 4; ++rt)
#pragma unroll
            for (int ct = 0; ct < 4; ++ct) {
                acc[rt][ct] = __builtin_amdgcn_mfma_f32_16x16x32_bf16(ah[rt], bh[ct], acc[rt][ct], 0, 0, 0);
                acc[rt][ct] = __builtin_amdgcn_mfma_f32_16x16x32_bf16(ah[rt], bl[ct], acc[rt][ct], 0, 0, 0);
                acc[rt][ct] = __builtin_amdgcn_mfma_f32_16x16x32_bf16(al[rt], bh[ct], acc[rt][ct], 0, 0, 0);
            }
    }

    // epilogue: direct fp32 stores + optional column stats
    float cs[4] = {0.f, 0.f, 0.f, 0.f}, cq[4] = {0.f, 0.f, 0.f, 0.f};
#pragma unroll
    for (int rt = 0; rt < 4; ++rt) {
#pragma unroll
        for (int i = 0; i < 4; ++i) {
            int row = wr + rt * 16 + q * 4 + i;
            int gr = row0 + row;
            if (gr < N) {
                float sc = rowScale ? rowScale[gr] : 1.f;
#pragma unroll
                for (int ct = 0; ct < 4; ++ct) {
                    int colg = wc + ct * 16 + lm;
                    float v = acc[rt][ct][i];
                    if (bias) v += bias[colg];
                    if (doRelu) v = fmaxf(v, 0.f);
                    v *= sc;
                    C[(size_t)gr * DIMC + colg] = v;
                    if (statsOut) { cs[ct] += v; cq[ct] = fmaf(v, v, cq[ct]); }
                }
            }
        }
    }
    if (statsOut) {
        sStats[tid] = 0.f;
        __syncthreads();
#pragma unroll
        for (int ct = 0; ct < 4; ++ct) {
            int colg = wc + ct * 16 + lm;
            atomicAdd(&sStats[colg], cs[ct]);
            atomicAdd(&sStats[128 + colg], cq[ct]);
        }
        __syncthreads();
        atomicAdd(&statsOut[tid], sStats[tid]);
    }
}

// ---------------- BN coefficients: sums -> (scale, shift) ----------------

__global__ void k_bn_coef(const float* __restrict__ bnsum, const float* __restrict__ gamma,
                          const float* __restrict__ beta, float* __restrict__ coef, float invN) {
    int c = threadIdx.x;  // 128
    float mu  = bnsum[c] * invN;
    float var = bnsum[128 + c] * invN - mu * mu;
    float inv = rsqrtf(var + 1e-5f);
    float s = gamma[c] * inv;
    coef[c] = s;
    coef[128 + c] = beta[c] - mu * s;
}

// ---------------- CSR gather aggregation (fp32) ----------------

__global__ void k_gather_gcn(const float4* __restrict__ t, const int* __restrict__ rowptr,
                             const int* __restrict__ col, const float* __restrict__ dis,
                             const float4* __restrict__ bias, float4* __restrict__ out, int N) {
    int i = blockIdx.x * blockDim.x + threadIdx.x;
    int node = i >> 5, c4 = i & 31;
    if (node >= N) return;
    int s = rowptr[node], e = rowptr[node + 1];
    float4 acc = t[(size_t)node * 32 + c4];
    for (int k = s; k < e; ++k) {
        float4 v = t[(size_t)col[k] * 32 + c4];
        acc.x += v.x; acc.y += v.y; acc.z += v.z; acc.w += v.w;
    }
    float d = dis[node];
    float4 b = bias[c4];
    float4 o;
    o.x = fmaxf(acc.x * d + b.x, 0.f);
    o.y = fmaxf(acc.y * d + b.y, 0.f);
    o.z = fmaxf(acc.z * d + b.z, 0.f);
    o.w = fmaxf(acc.w * d + b.w, 0.f);
    out[(size_t)node * 32 + c4] = o;
}

__global__ void k_gather_gin(const float4* __restrict__ t, const int* __restrict__ rowptr,
                             const int* __restrict__ col, const float4* __restrict__ bias,
                             float4* __restrict__ out, int N) {
    int i = blockIdx.x * blockDim.x + threadIdx.x;
    int node = i >> 5, c4 = i & 31;
    if (node >= N) return;
    int s = rowptr[node], e = rowptr[node + 1];
    float4 acc = t[(size_t)node * 32 + c4];
    for (int k = s; k < e; ++k) {
        float4 v = t[(size_t)col[k] * 32 + c4];
        acc.x += v.x; acc.y += v.y; acc.z += v.z; acc.w += v.w;
    }
    float4 b = bias[c4];
    float4 o;
    o.x = fmaxf(acc.x + b.x, 0.f);
    o.y = fmaxf(acc.y + b.y, 0.f);
    o.z = fmaxf(acc.z + b.z, 0.f);
    o.w = fmaxf(acc.w + b.w, 0.f);
    out[(size_t)node * 32 + c4] = o;
}

// ---------------- segment max ----------------

// GIN groups 0..4: per-layer BN outputs (affine on the fly), product, sum
__global__ void k_segmax_gin_all(const float* __restrict__ h0, const float* __restrict__ h1,
                                 const float* __restrict__ h2, const float* __restrict__ coef,
                                 const int* __restrict__ start, float* __restrict__ out) {
    int g = blockIdx.x, c = threadIdx.x;
    float s0 = coef[c],       t0 = coef[128 + c];
    float s1 = coef[256 + c], t1 = coef[384 + c];
    float s2 = coef[512 + c], t2 = coef[640 + c];
    int s = start[g], e = start[g + 1];
    float m0 = -INFINITY, m1 = -INFINITY, m2 = -INFINITY, mm = -INFINITY, me = -INFINITY;
    for (int n = s; n < e; ++n) {
        size_t idx = (size_t)n * DIMC + c;
        float a0 = fmaf(h0[idx], s0, t0);
        float a1 = fmaf(h1[idx], s1, t1);
        float a2 = fmaf(h2[idx], s2, t2);
        m0 = fmaxf(m0, a0); m1 = fmaxf(m1, a1); m2 = fmaxf(m2, a2);
        mm = fmaxf(mm, a0 * a1 * a2);
        me = fmaxf(me, a0 + a1 + a2);
    }
    size_t o = (size_t)g * REPW + c;
    out[o]            = m0;
    out[o + 1 * DIMC] = m1;
    out[o + 2 * DIMC] = m2;
    out[o + 3 * DIMC] = mm;
    out[o + 4 * DIMC] = me;
}

__global__ void k_segmax_gcn(const float* __restrict__ G1, const float* __restrict__ G2,
                             const int* __restrict__ start, float* __restrict__ out) {
    int g = blockIdx.x, c = threadIdx.x;
    int s = start[g], e = start[g + 1];
    float m1 = -INFINITY, m2 = -INFINITY, ma = -INFINITY, mm = -INFINITY;
    for (int n = s; n < e; ++n) {
        float a = G1[(size_t)n * DIMC + c], b = G2[(size_t)n * DIMC + c];
        m1 = fmaxf(m1, a); m2 = fmaxf(m2, b);
        ma = fmaxf(ma, a + b); mm = fmaxf(mm, a * b);
    }
    size_t o = (size_t)g * REPW + c;
    out[o + 5 * DIMC] = m1;
    out[o + 6 * DIMC] = m2;
    out[o + 7 * DIMC] = ma;
    out[o + 8 * DIMC] = mm;
}

// ---------------- launch ----------------

extern "C" void kernel_launch(void* const* d_in, const int* in_sizes, int n_in,
                              void* d_out, int out_size, void* d_ws, size_t ws_size,
                              hipStream_t stream) {
    const float* x       = (const float*)d_in[0];
    const int*   ei      = (const int*)d_in[1];
    const int*   batch   = (const int*)d_in[2];
    const float* gcn1_W  = (const float*)d_in[4];
    const float* gcn1_b  = (const float*)d_in[5];
    const float* gcn2_W  = (const float*)d_in[6];
    const float* gcn2_b  = (const float*)d_in[7];
    const float* gin0_w1 = (const float*)d_in[8];
    const float* gin0_b1 = (const float*)d_in[9];
    const float* gin0_w2 = (const float*)d_in[10];
    const float* gin0_b2 = (const float*)d_in[11];
    const float* gin_w1  = (const float*)d_in[12];
    const float* gin_b1  = (const float*)d_in[13];
    const float* gin_w2  = (const float*)d_in[14];
    const float* gin_b2  = (const float*)d_in[15];
    const float* bn_g    = (const float*)d_in[16];
    const float* bn_b    = (const float*)d_in[17];
    float* out = (float*)d_out;

    const int N = in_sizes[0] / FINC;   // 100000
    const int E = in_sizes[1] / 2;      // 400000
    const int G = out_size / REPW;      // 2500
    const int* srcv = ei;
    const int* dstv = ei + E;

    char* ws = (char*)d_ws;
    size_t off = 0;
    auto alloc = [&](size_t bytes) { char* p = ws + off; off += (bytes + 255) & ~(size_t)255; return p; };
    int*   cnt     = (int*)alloc(N * 4);
    int*   rowptr  = (int*)alloc((N + 1) * 4);
    int*   cursor  = (int*)alloc(N * 4);
    int*   col     = (int*)alloc(E * 4);
    float* dis     = (float*)alloc(N * 4);
    float* bnsum   = (float*)alloc(768 * 4);   // 3 layers x (sum[128], sumsq[128])
    float* coef    = (float*)alloc(768 * 4);   // 3 layers x (scale[128], shift[128])
    int*   start   = (int*)alloc((G + 1) * 4);
    int*   tileSum = (int*)alloc(256 * 4);
    int*   tileOff = (int*)alloc(256 * 4);
    const size_t wtElems = 2 * (size_t)128 * 96 + 6 * (size_t)128 * 128;
    unsigned short* whi = (unsigned short*)alloc(wtElems * 2);
    unsigned short* wlo = (unsigned short*)alloc(wtElems * 2);
    float* bufT    = (float*)alloc((size_t)N * DIMC * 4);   // t scratch / GCN t
    float* bufZ    = (float*)alloc((size_t)N * DIMC * 4);   // z scratch / GCN g1
    float* h0      = (float*)alloc((size_t)N * DIMC * 4);   // GIN h0 raw / GCN g2
    float* h1      = (float*)alloc((size_t)N * DIMC * 4);
    float* h2      = (float*)alloc((size_t)N * DIMC * 4);
    (void)ws_size; (void)n_in;

    const size_t o96 = (size_t)128 * 96, o128 = (size_t)128 * 128;
    const size_t woff[8] = {0, o96, 2 * o96, 2 * o96 + o128, 2 * o96 + 2 * o128,
                            2 * o96 + 3 * o128, 2 * o96 + 4 * o128, 2 * o96 + 5 * o128};
    // order: gcn1, gin0_w1, gcn2, gin0_w2, gin_w1[0], gin_w1[1], gin_w2[0], gin_w2[1]

    const int T = 256;
    auto cdiv = [](long a, long b) { return (int)((a + b - 1) / b); };
    const int gemmGrid = cdiv(N, 128);
    const int gatherGrid = cdiv((long)N * 32, T);
    const int nTiles = cdiv(N, SCAN_TILE);
    const float invN = 1.0f / (float)N;

    // ---- CSR build + norms + graph bounds + weight split ----
    k_fill_int<<<cdiv(N, T), T, 0, stream>>>(cnt, 0, N);
    k_count<<<cdiv(E, T), T, 0, stream>>>(dstv, cnt, E);
    k_tilesum<<<nTiles, T, 0, stream>>>(cnt, tileSum, N);
    k_tilescan<<<1, T, 0, stream>>>(tileSum, tileOff, rowptr, nTiles, N);
    k_tileemit<<<nTiles, T, 0, stream>>>(cnt, tileOff, rowptr, cursor, dis, N);
    k_scatter<<<cdiv(E, T), T, 0, stream>>>(srcv, dstv, cursor, col, E);
    k_bounds<<<cdiv(G + 1, T), T, 0, stream>>>(batch, start, N, G);
    k_fill<<<3, T, 0, stream>>>(bnsum, 0.f, 768);
    {
        dim3 g(64, 8);
        k_cvt_w<<<g, T, 0, stream>>>(gcn1_W, gin0_w1, gcn2_W, gin0_w2,
                                     gin_w1, gin_w1 + o128, gin_w2, gin_w2 + o128, whi, wlo);
    }

    // ---- GCN branch ----
    k_gemm_mfma3<FINC, 96><<<gemmGrid, T, 0, stream>>>(x, whi + woff[0], wlo + woff[0],
                                                       nullptr, dis, nullptr, nullptr, nullptr, bufT, N, 0);
    k_gather_gcn<<<gatherGrid, T, 0, stream>>>((const float4*)bufT, rowptr, col, dis,
                                               (const float4*)gcn1_b, (float4*)bufZ, N);   // g1
    k_gemm_mfma3<DIMC, 128><<<gemmGrid, T, 0, stream>>>(bufZ, whi + woff[2], wlo + woff[2],
                                                        nullptr, dis, nullptr, nullptr, nullptr, bufT, N, 0);
    k_gather_gcn<<<gatherGrid, T, 0, stream>>>((const float4*)bufT, rowptr, col, dis,
                                               (const float4*)gcn2_b, (float4*)h0, N);     // g2
    k_segmax_gcn<<<G, DIMC, 0, stream>>>(bufZ, h0, start, out);                            // groups 5..8

    // ---- GIN layers (BN deferred: raw relu'd h stored; affine applied by consumers) ----
    const int w1i[3] = {1, 4, 5};
    const int w2i[3] = {3, 6, 7};
    const float* b1s[3] = {gin0_b1, gin_b1, gin_b1 + DIMC};
    const float* b2s[3] = {gin0_b2, gin_b2, gin_b2 + DIMC};
    float* hs[3] = {h0, h1, h2};

    for (int L = 0; L < 3; ++L) {
        if (L == 0)
            k_gemm_mfma3<FINC, 96><<<gemmGrid, T, 0, stream>>>(x, whi + woff[1], wlo + woff[1],
                                                               nullptr, nullptr, nullptr, nullptr, nullptr,
                                                               bufT, N, 0);
        else
            k_gemm_mfma3<DIMC, 128><<<gemmGrid, T, 0, stream>>>(hs[L - 1], whi + woff[w1i[L]], wlo + woff[w1i[L]],
                                                                nullptr, nullptr,
                                                                coef + (L - 1) * 256, coef + (L - 1) * 256 + 128,
                                                                nullptr, bufT, N, 0);
        k_gather_gin<<<gatherGrid, T, 0, stream>>>((const float4*)bufT, rowptr, col,
                                                   (const float4*)b1s[L], (float4*)bufZ, N);
        k_gemm_mfma3<DIMC, 128><<<gemmGrid, T, 0, stream>>>(bufZ, whi + woff[w2i[L]], wlo + woff[w2i[L]],
                                                            b2s[L], nullptr, nullptr, nullptr,
                                                            bnsum + L * 256, hs[L], N, 1);
        k_bn_coef<<<1, DIMC, 0, stream>>>(bnsum + L * 256, bn_g + L * DIMC, bn_b + L * DIMC,
                                          coef + L * 256, invN);
    }

    k_segmax_gin_all<<<G, DIMC, 0, stream>>>(h0, h1, h2, coef, start, out);                // groups 0..4
}